// Round 16
// baseline (1393.812 us; speedup 1.0000x reference)
//
#include <hip/hip_runtime.h>

#define B 128
#define S 16
#define E 512
#define R 1000
#define K3 1536
#define NW0 1920   // init worklist: 128 b * 15 pairs
#define NWS 256    // per-step worklist: 128 b * 2 entries
#define NS (B * (R + 1))
#define SCALE 0.04419417382415922f

static __device__ __forceinline__ float sigm(float x) { return 1.f / (1.f + expf(-x)); }

// ---------- block reductions (256 threads) ----------
static __device__ __forceinline__ float brsum(float v, float* sb) {
  int tid = threadIdx.x;
  sb[tid] = v; __syncthreads();
  for (int s = 128; s > 0; s >>= 1) {
    if (tid < s) sb[tid] += sb[tid + s];
    __syncthreads();
  }
  float r = sb[0]; __syncthreads();
  return r;
}
static __device__ __forceinline__ float brmax(float v, float* sb) {
  int tid = threadIdx.x;
  sb[tid] = v; __syncthreads();
  for (int s = 128; s > 0; s >>= 1) {
    if (tid < s) sb[tid] = fmaxf(sb[tid], sb[tid + s]);
    __syncthreads();
  }
  float r = sb[0]; __syncthreads();
  return r;
}
// paired sum reduction: (v1,v2) -> (sb[0], sb2[0])
static __device__ __forceinline__ void brsum2(float v1, float v2, float* sb, float* sb2,
                                              float* o1, float* o2) {
  int tid = threadIdx.x;
  sb[tid] = v1; sb2[tid] = v2; __syncthreads();
  for (int s = 128; s > 0; s >>= 1) {
    if (tid < s) { sb[tid] += sb[tid + s]; sb2[tid] += sb2[tid + s]; }
    __syncthreads();
  }
  *o1 = sb[0]; *o2 = sb2[0]; __syncthreads();
}

#define TILE_FMA \
  _Pragma("unroll") \
  for (int k = 0; k < 16; ++k) { \
    float4 a4 = *(const float4*)&As[k][ty * 4]; \
    float4 w4 = *(const float4*)&Ws[k][tx * 4]; \
    acc[0][0] = fmaf(a4.x, w4.x, acc[0][0]); acc[0][1] = fmaf(a4.x, w4.y, acc[0][1]); \
    acc[0][2] = fmaf(a4.x, w4.z, acc[0][2]); acc[0][3] = fmaf(a4.x, w4.w, acc[0][3]); \
    acc[1][0] = fmaf(a4.y, w4.x, acc[1][0]); acc[1][1] = fmaf(a4.y, w4.y, acc[1][1]); \
    acc[1][2] = fmaf(a4.y, w4.z, acc[1][2]); acc[1][3] = fmaf(a4.y, w4.w, acc[1][3]); \
    acc[2][0] = fmaf(a4.z, w4.x, acc[2][0]); acc[2][1] = fmaf(a4.z, w4.y, acc[2][1]); \
    acc[2][2] = fmaf(a4.z, w4.z, acc[2][2]); acc[2][3] = fmaf(a4.z, w4.w, acc[2][3]); \
    acc[3][0] = fmaf(a4.w, w4.x, acc[3][0]); acc[3][1] = fmaf(a4.w, w4.y, acc[3][1]); \
    acc[3][2] = fmaf(a4.w, w4.z, acc[3][2]); acc[3][3] = fmaf(a4.w, w4.w, acc[3][3]); \
  }

// 32-row-tile inner product: acc[2][4], A in As[16][32], W in Ws[16][64]
#define TILE_FMA32 \
  _Pragma("unroll") \
  for (int k = 0; k < 16; ++k) { \
    float2 a2 = *(const float2*)&As[k][ty * 2]; \
    float4 w4 = *(const float4*)&Ws[k][tx * 4]; \
    acc[0][0] = fmaf(a2.x, w4.x, acc[0][0]); acc[0][1] = fmaf(a2.x, w4.y, acc[0][1]); \
    acc[0][2] = fmaf(a2.x, w4.z, acc[0][2]); acc[0][3] = fmaf(a2.x, w4.w, acc[0][3]); \
    acc[1][0] = fmaf(a2.y, w4.x, acc[1][0]); acc[1][1] = fmaf(a2.y, w4.y, acc[1][1]); \
    acc[1][2] = fmaf(a2.y, w4.z, acc[1][2]); acc[1][3] = fmaf(a2.y, w4.w, acc[1][3]); \
  }

// ---------- generic tiled gemm (standalone body — VGPR~44 codegen) ----------
__global__ __launch_bounds__(256) void k_gemm(const float* __restrict__ A, int lda, int M,
                                              const float* __restrict__ W, int N, int K,
                                              const float* __restrict__ bias, float scale,
                                              float* __restrict__ C, int ldc) {
  __shared__ float As[16][64];
  __shared__ float Ws[16][64];
  int tid = threadIdx.x;
  int mBase = blockIdx.y * 64;
  int nBase = blockIdx.x * 64;
  int tx = tid & 15, ty = tid >> 4;
  int li = tid & 63;
  int lk = (tid >> 6) * 4;
  float acc[4][4] = {{0.f,0.f,0.f,0.f},{0.f,0.f,0.f,0.f},{0.f,0.f,0.f,0.f},{0.f,0.f,0.f,0.f}};
  int m = mBase + li;
  const float* Arow = (m < M) ? (A + (size_t)m * lda) : nullptr;
  int n = nBase + li;
  const float* Wrow = (n < N) ? (W + (size_t)n * K) : nullptr;

  float4 av = Arow ? *(const float4*)(Arow + lk) : make_float4(0.f, 0.f, 0.f, 0.f);
  float4 wv = Wrow ? *(const float4*)(Wrow + lk) : make_float4(0.f, 0.f, 0.f, 0.f);

  for (int k0 = 0; k0 < K; k0 += 16) {
    As[lk + 0][li] = av.x; As[lk + 1][li] = av.y;
    As[lk + 2][li] = av.z; As[lk + 3][li] = av.w;
    Ws[lk + 0][li] = wv.x; Ws[lk + 1][li] = wv.y;
    Ws[lk + 2][li] = wv.z; Ws[lk + 3][li] = wv.w;
    __syncthreads();
    if (k0 + 16 < K) {
      av = Arow ? *(const float4*)(Arow + k0 + 16 + lk) : make_float4(0.f, 0.f, 0.f, 0.f);
      wv = Wrow ? *(const float4*)(Wrow + k0 + 16 + lk) : make_float4(0.f, 0.f, 0.f, 0.f);
    }
    TILE_FMA
    __syncthreads();
  }
#pragma unroll
  for (int r = 0; r < 4; ++r) {
    int mm = mBase + ty * 4 + r;
    if (mm >= M) continue;
#pragma unroll
    for (int c = 0; c < 4; ++c) {
      int nn = nBase + tx * 4 + c;
      if (nn >= N) continue;
      float v = acc[r][c] * scale;
      if (bias) v += bias[nn];
      C[(size_t)mm * ldc + nn] = v;
    }
  }
}

// ---------- dual-output gemm: n<N1 -> W1,C1 ; else W2,C2 ----------
__global__ __launch_bounds__(256) void k_gemmD(const float* __restrict__ A, int lda, int M,
                                               const float* __restrict__ W1, int N1,
                                               const float* __restrict__ b1,
                                               float* __restrict__ C1, int ldc1,
                                               const float* __restrict__ W2, int N2,
                                               float* __restrict__ C2, int ldc2, int K) {
  __shared__ float As[16][64];
  __shared__ float Ws[16][64];
  int tid = threadIdx.x;
  int mBase = blockIdx.y * 64;
  int nBase = blockIdx.x * 64;
  int tx = tid & 15, ty = tid >> 4;
  int li = tid & 63;
  int lk = (tid >> 6) * 4;
  float acc[4][4] = {{0.f,0.f,0.f,0.f},{0.f,0.f,0.f,0.f},{0.f,0.f,0.f,0.f},{0.f,0.f,0.f,0.f}};
  int m = mBase + li;
  const float* Arow = (m < M) ? (A + (size_t)m * lda) : nullptr;
  int n = nBase + li;
  const float* Wrow = nullptr;
  if (n < N1) Wrow = W1 + (size_t)n * K;
  else if (n < N1 + N2) Wrow = W2 + (size_t)(n - N1) * K;

  float4 av = Arow ? *(const float4*)(Arow + lk) : make_float4(0.f, 0.f, 0.f, 0.f);
  float4 wv = Wrow ? *(const float4*)(Wrow + lk) : make_float4(0.f, 0.f, 0.f, 0.f);

  for (int k0 = 0; k0 < K; k0 += 16) {
    As[lk + 0][li] = av.x; As[lk + 1][li] = av.y;
    As[lk + 2][li] = av.z; As[lk + 3][li] = av.w;
    Ws[lk + 0][li] = wv.x; Ws[lk + 1][li] = wv.y;
    Ws[lk + 2][li] = wv.z; Ws[lk + 3][li] = wv.w;
    __syncthreads();
    if (k0 + 16 < K) {
      av = Arow ? *(const float4*)(Arow + k0 + 16 + lk) : make_float4(0.f, 0.f, 0.f, 0.f);
      wv = Wrow ? *(const float4*)(Wrow + k0 + 16 + lk) : make_float4(0.f, 0.f, 0.f, 0.f);
    }
    TILE_FMA
    __syncthreads();
  }
#pragma unroll
  for (int r = 0; r < 4; ++r) {
    int mm = mBase + ty * 4 + r;
    if (mm >= M) continue;
#pragma unroll
    for (int c = 0; c < 4; ++c) {
      int nn = nBase + tx * 4 + c;
      if (nn < N1) {
        float v = acc[r][c];
        if (b1) v += b1[nn];
        C1[(size_t)mm * ldc1 + nn] = v;
      } else if (nn < N1 + N2) {
        C2[(size_t)mm * ldc2 + (nn - N1)] = acc[r][c];
      }
    }
  }
}

// ---------- 64x64 transpose tile (device) ----------
static __device__ void dev_tr64(float (*t)[65], int tid, const float* __restrict__ src,
                                int Cc, float* __restrict__ dst, int ldd, int bx, int by) {
  int tx = tid & 15, ty = tid >> 4;
  int rb = by * 64, cb = bx * 64;
#pragma unroll
  for (int i = 0; i < 4; ++i) {
    int r = rb + ty + i * 16;
    float4 v = *(const float4*)(src + (size_t)r * Cc + cb + tx * 4);
    t[ty + i * 16][tx * 4 + 0] = v.x; t[ty + i * 16][tx * 4 + 1] = v.y;
    t[ty + i * 16][tx * 4 + 2] = v.z; t[ty + i * 16][tx * 4 + 3] = v.w;
  }
  __syncthreads();
#pragma unroll
  for (int i = 0; i < 4; ++i) {
    int c = cb + ty + i * 16;
    float4 v;
    v.x = t[tx * 4 + 0][ty + i * 16]; v.y = t[tx * 4 + 1][ty + i * 16];
    v.z = t[tx * 4 + 2][ty + i * 16]; v.w = t[tx * 4 + 3][ty + i * 16];
    *(float4*)(dst + (size_t)c * ldd + rb + tx * 4) = v;
  }
}

// ---------- setup L1: Wih transpose + initwl + pad + out14 + Mqk NT-gemm + v12/bw/wv3/c0 ----
__global__ __launch_bounds__(256) void k_prep(const float* __restrict__ Wq,
                                              const float* __restrict__ Wk,
                                              const float* __restrict__ Wih,
                                              float* __restrict__ Wbig,
                                              int* __restrict__ pos,
                                              int* __restrict__ wlb,
                                              int* __restrict__ wlL,
                                              int* __restrict__ wlR,
                                              float* __restrict__ outp,
                                              float* __restrict__ Gbig,
                                              const float* __restrict__ bq,
                                              const float* __restrict__ bk,
                                              float* __restrict__ v12,
                                              float* __restrict__ bw,
                                              float* __restrict__ wv3,
                                              float* __restrict__ c0s) {
  __shared__ float t[64][65];
  int blk = blockIdx.x, tid = threadIdx.x;
  if (blk < 192) {
    dev_tr64(t, tid, Wih, E, Wbig + (size_t)1024 * K3, K3, blk & 7, blk >> 3);
  } else if (blk < 200) {
    int idx = (blk - 192) * 256 + tid;
    if (idx < B * 16) pos[idx] = idx & 15;
    if (idx < NW0) {
      wlb[idx] = idx / 15;
      int i = idx % 15;
      wlL[idx] = i;
      wlR[idx] = i + 1;
    }
    if (idx < B) outp[NS + idx * 16 + 14] = 0.f;  // loss col 14 is identically 0
  } else if (blk < 208) {
    int idx = (blk - 200) * 256 + tid;
    for (int i = idx; i < 24 * K3; i += 8 * 256) Wbig[(size_t)1000 * K3 + i] = 0.f;
  } else if (blk < 272) {
    // Mqk[i,f] = sum_e Wq[e,i]*Wk[e,f]  (NT gemm, no transposes needed)
    int j = blk - 208;
    int fT = (j & 7) * 64, iT = (j >> 3) * 64;
    float (*As)[64] = (float(*)[64])&t[0][0];
    float (*Ws)[64] = (float(*)[64])&t[20][0];
    int tx = tid & 15, ty = tid >> 4;
    int li = tid & 63, lk = (tid >> 6) * 4;
    float acc[4][4] = {{0.f,0.f,0.f,0.f},{0.f,0.f,0.f,0.f},{0.f,0.f,0.f,0.f},{0.f,0.f,0.f,0.f}};
    float a0 = Wq[(size_t)(lk + 0) * E + iT + li];
    float a1 = Wq[(size_t)(lk + 1) * E + iT + li];
    float a2 = Wq[(size_t)(lk + 2) * E + iT + li];
    float a3 = Wq[(size_t)(lk + 3) * E + iT + li];
    float w0 = Wk[(size_t)(lk + 0) * E + fT + li];
    float w1 = Wk[(size_t)(lk + 1) * E + fT + li];
    float w2 = Wk[(size_t)(lk + 2) * E + fT + li];
    float w3 = Wk[(size_t)(lk + 3) * E + fT + li];
    for (int e0 = 0; e0 < E; e0 += 16) {
      As[lk + 0][li] = a0; As[lk + 1][li] = a1;
      As[lk + 2][li] = a2; As[lk + 3][li] = a3;
      Ws[lk + 0][li] = w0; Ws[lk + 1][li] = w1;
      Ws[lk + 2][li] = w2; Ws[lk + 3][li] = w3;
      __syncthreads();
      if (e0 + 16 < E) {
        a0 = Wq[(size_t)(e0 + 16 + lk + 0) * E + iT + li];
        a1 = Wq[(size_t)(e0 + 16 + lk + 1) * E + iT + li];
        a2 = Wq[(size_t)(e0 + 16 + lk + 2) * E + iT + li];
        a3 = Wq[(size_t)(e0 + 16 + lk + 3) * E + iT + li];
        w0 = Wk[(size_t)(e0 + 16 + lk + 0) * E + fT + li];
        w1 = Wk[(size_t)(e0 + 16 + lk + 1) * E + fT + li];
        w2 = Wk[(size_t)(e0 + 16 + lk + 2) * E + fT + li];
        w3 = Wk[(size_t)(e0 + 16 + lk + 3) * E + fT + li];
      }
      TILE_FMA
      __syncthreads();
    }
#pragma unroll
    for (int r = 0; r < 4; ++r)
#pragma unroll
      for (int c = 0; c < 4; ++c)
        Gbig[(size_t)(1000 + iT + ty * 4 + r) * E + fT + tx * 4 + c] = acc[r][c];
  } else if (blk < 274) {
    int i = (blk - 272) * 256 + tid;
    float s = 0.f;
    for (int e = 0; e < E; ++e) s += Wq[(size_t)e * E + i] * bk[e] + bq[e] * Wk[(size_t)e * E + i];
    v12[i] = s;
  } else if (blk < 276) {
    int i = (blk - 274) * 256 + tid;
    float s = 0.f;
    for (int e = 0; e < E; ++e) s += bk[e] * Wq[(size_t)e * E + i];
    bw[i] = s;
  } else if (blk < 278) {
    int f = (blk - 276) * 256 + tid;
    float s = 0.f;
    for (int e = 0; e < E; ++e) s += bq[e] * Wk[(size_t)e * E + f];
    wv3[f] = s;
  } else {
    float* sb = &t[0][0];
    float p = 0.f;
    for (int e = tid; e < E; e += 256) p += bq[e] * bk[e];
    float s = brsum(p, sb);
    if (tid == 0) c0s[0] = s;
  }
}

// ---------- setup B: H1V vocab h1 [0,1000) | GI gather [1000,3048) | SCT zero | gb ----------
__global__ __launch_bounds__(256) void k_setupB(const int* __restrict__ tokens,
                                                const float* __restrict__ Wbig,
                                                const float* __restrict__ bih,
                                                const float* __restrict__ bhh,
                                                const float* __restrict__ emb,
                                                const float* __restrict__ wv3,
                                                float* __restrict__ GI,
                                                float* __restrict__ H1V,
                                                float* __restrict__ SCT,
                                                float* __restrict__ gb) {
  int blk = blockIdx.x, tid = threadIdx.x;
  if (blk < 1000) {
    const float* ew = Wbig + (size_t)blk * K3;
    float* h = H1V + (size_t)blk * E;
    for (int e = tid; e < E; e += 256) {
      float g0 = ew[e] + bih[e];
      float g1 = ew[E + e] + bih[E + e];
      float g2 = ew[2 * E + e] + bih[2 * E + e];
      float r = sigm(g0 + bhh[e]);
      float z = sigm(g1 + bhh[E + e]);
      h[e] = (1.f - z) * tanhf(g2 + r * bhh[2 * E + e]);
    }
  } else if (blk < 1000 + B * S) {
    int p = blk - 1000;
    int tok = tokens[p];
    const float4* src = (const float4*)(Wbig + (size_t)tok * K3);
    const float4* bv = (const float4*)bih;
    float4* dst = (float4*)(GI + (size_t)p * K3);
    for (int i = tid; i < K3 / 4; i += 256) {
      float4 a = src[i], b = bv[i];
      dst[i] = make_float4(a.x + b.x, a.y + b.y, a.z + b.z, a.w + b.w);
    }
  } else if (blk < 1000 + B * S + 8) {
    int rb = blk - (1000 + B * S);
    for (int m = rb * 16; m < rb * 16 + 16; ++m) {
      float* r = SCT + (size_t)m * K3;
      for (int n = tid; n < 1512; n += 256) r[n] = 0.f;
    }
  } else {
    int r = (blk - (1000 + B * S + 8)) * 256 + tid;
    if (r < R) {
      const float* er = emb + (size_t)r * E;
      float s = 0.f;
      for (int f = 0; f < E; ++f) s += er[f] * wv3[f];
      gb[r] = s;  // raw: score adds (gb + SP.bw + c0)
    }
  }
}

// ---------- setup pairc: compute PAIR/SCR from vocab tables + gather position caches ----
__global__ __launch_bounds__(256) void k_pairc0(const int* __restrict__ tokens,
                                                const float* __restrict__ GI,
                                                const float* __restrict__ GHCV,
                                                const float* __restrict__ H1V,
                                                const float* __restrict__ wfc,
                                                const float* __restrict__ bfc,
                                                float* __restrict__ PAIR,
                                                float* __restrict__ SCR,
                                                float* __restrict__ H1P,
                                                float* __restrict__ GHCP) {
  __shared__ float sb[256];
  int w = blockIdx.x, tid = threadIdx.x;
  int b = w / 15, i = w % 15;
  int lp = b * 16 + i;
  int tok = tokens[lp];
  const float* gr = GI + (size_t)(lp + 1) * K3;
  const float* gh = GHCV + (size_t)tok * K3;
  const float* h = H1V + (size_t)tok * E;
  float* ghp = GHCP + (size_t)lp * K3;
  float* hp = H1P + (size_t)lp * E;
  float* p = PAIR + (size_t)lp * E;
  float part = 0.f;
  for (int e = tid; e < E; e += 256) {
    float g0 = gh[e], g1 = gh[E + e], g2 = gh[2 * E + e], he = h[e];
    ghp[e] = g0; ghp[E + e] = g1; ghp[2 * E + e] = g2; hp[e] = he;
    float r = sigm(gr[e] + g0);
    float z = sigm(gr[E + e] + g1);
    float n = tanhf(gr[2 * E + e] + r * g2);
    float pv = (1.f - z) * n + z * he;
    p[e] = pv;
    part += pv * wfc[e];
  }
  float d = brsum(part, sb);
  if (tid == 0) SCR[lp] = sigm(d + bfc[0]);
}

// ---------- GHC split-K gemm, 32-row tiles, position-indirect: grid (24, 4, 2) ----------
__global__ __launch_bounds__(256) void k_ghcs(const int* __restrict__ xdst,
                                              const float* __restrict__ H1P,
                                              const float* __restrict__ Whh,
                                              float* __restrict__ GHCP) {
  __shared__ float As[16][32];
  __shared__ float Ws[16][64];
  __shared__ int sp[32];
  int tid = threadIdx.x;
  int nBase = blockIdx.x * 64;
  int mBase = blockIdx.y * 32;
  int kbeg = blockIdx.z * 256;
  if (tid < 32) sp[tid] = xdst[mBase + tid];
  __syncthreads();
  int tx = tid & 15, ty = tid >> 4;
  int ar = tid & 31, ak = (tid >> 5) * 2;
  int li = tid & 63, lk = (tid >> 6) * 4;
  float acc[2][4] = {{0.f,0.f,0.f,0.f},{0.f,0.f,0.f,0.f}};
  const float* Arow = H1P + (size_t)sp[ar] * E + kbeg;
  const float* Wrow = Whh + (size_t)(nBase + li) * E + kbeg;
  float2 av = *(const float2*)(Arow + ak);
  float4 wv = *(const float4*)(Wrow + lk);
  for (int k0 = 0; k0 < 256; k0 += 16) {
    As[ak + 0][ar] = av.x; As[ak + 1][ar] = av.y;
    Ws[lk + 0][li] = wv.x; Ws[lk + 1][li] = wv.y;
    Ws[lk + 2][li] = wv.z; Ws[lk + 3][li] = wv.w;
    __syncthreads();
    if (k0 + 16 < 256) {
      av = *(const float2*)(Arow + k0 + 16 + ak);
      wv = *(const float4*)(Wrow + k0 + 16 + lk);
    }
    TILE_FMA32
    __syncthreads();
  }
#pragma unroll
  for (int r = 0; r < 2; ++r) {
    size_t crow = (size_t)sp[ty * 2 + r] * K3;
#pragma unroll
    for (int c = 0; c < 4; ++c) {
      int nn = nBase + tx * 4 + c;
      atomicAdd(&GHCP[crow + nn], acc[r][c]);
    }
  }
}

// ---------- pair + fc score (position-keyed H1P/GHCP caches) ----------
__global__ __launch_bounds__(256) void k_pairc(const int* __restrict__ wlb,
                                               const int* __restrict__ wlL,
                                               const int* __restrict__ wlR,
                                               const float* __restrict__ GI,
                                               const float* __restrict__ GHCP,
                                               const float* __restrict__ H1P,
                                               const float* __restrict__ wfc,
                                               const float* __restrict__ bfc,
                                               float* __restrict__ PAIR,
                                               float* __restrict__ SCR) {
  __shared__ float sb[256];
  int w = blockIdx.x, tid = threadIdx.x;
  int b = wlb[w], ls = wlL[w], rs = wlR[w];
  int lp = b * 16 + ls;
  const float* gr = GI + (size_t)(b * 16 + rs) * K3;
  const float* gh = GHCP + (size_t)lp * K3;
  const float* h = H1P + (size_t)lp * E;
  float* p = PAIR + (size_t)lp * E;
  float part = 0.f;
  for (int e = tid; e < E; e += 256) {
    float r = sigm(gr[e] + gh[e]);
    float z = sigm(gr[E + e] + gh[E + e]);
    float n = tanhf(gr[2 * E + e] + r * gh[2 * E + e]);
    float pv = (1.f - z) * n + z * h[e];
    p[e] = pv;
    part += pv * wfc[e];
  }
  float d = brsum(part, sb);
  if (tid == 0) SCR[b * 16 + ls] = sigm(d + bfc[0]);
}

// ---------- fused sel + scores split-K gemm, 32-row tiles: grid (24, 4, 2) ----------
// z==0 x==0: pos/wl/xdst bookkeeping; z==1 x<16: GI[xdst]=bih (2 rows);
// z==0 x in [8,24): GHCP[xdst]=bhh (2 rows).
__global__ __launch_bounds__(256) void k_qscsel(const float* __restrict__ PAIR,
                                                const float* __restrict__ SCR,
                                                const int* __restrict__ pin,
                                                int* __restrict__ pout,
                                                int* __restrict__ wlb,
                                                int* __restrict__ wlL,
                                                int* __restrict__ wlR,
                                                int* __restrict__ xdst,
                                                const float* __restrict__ Gbig,
                                                float* __restrict__ SCT,
                                                float* __restrict__ GI,
                                                const float* __restrict__ bih,
                                                float* __restrict__ GHCP,
                                                const float* __restrict__ bhh,
                                                int P, int finalMode) {
  __shared__ float As[16][32];
  __shared__ float Ws[16][64];
  __shared__ int sxd[32];
  int tid = threadIdx.x;
  int nBase = blockIdx.x * 64;
  int mBase = blockIdx.y * 32;
  int kbeg = blockIdx.z * 256;
  if (tid < 32) {
    int b = mBase + tid;
    if (finalMode) {
      int xr = b * 16 + pin[b * 16];
      sxd[tid] = xr;
      if (blockIdx.x == 0 && blockIdx.z == 0) xdst[b] = xr;
    } else {
      int L = P + 1;
      int lp[16];
      for (int i = 0; i < L; ++i) lp[i] = pin[b * 16 + i];
      float best = -1e30f; int sel = 0;
      for (int i = 0; i < P; ++i) {
        float v = SCR[b * 16 + lp[i]];
        if (v > best) { best = v; sel = i; }
      }
      int r1i = (sel + 2 < L) ? sel + 2 : L - 1;
      int l1 = lp[sel], r1 = lp[r1i];
      int l0 = (sel > 0) ? lp[sel - 1] : l1;
      int r0 = (sel > 0) ? lp[sel] : r1;
      sxd[tid] = b * 16 + l1;
      if (blockIdx.x == 0 && blockIdx.z == 0) {
        wlb[2 * b] = b;     wlL[2 * b] = l0;     wlR[2 * b] = r0;
        wlb[2 * b + 1] = b; wlL[2 * b + 1] = l1; wlR[2 * b + 1] = r1;
        xdst[b] = b * 16 + l1;
        for (int i = 0; i < L - 1; ++i)
          pout[b * 16 + i] = (i <= sel) ? lp[i] : lp[i + 1];
      }
    }
  }
  __syncthreads();
  // Early cache-row inits (duplicate-free partition, deterministic values):
  // old GI[xdst]/GHCP[xdst] have no readers after this point this step.
  if (!finalMode) {
    if (blockIdx.z == 1 && blockIdx.x < 16) {
#pragma unroll
      for (int r = 0; r < 2; ++r) {
        float4* g = (float4*)(GI + (size_t)sxd[blockIdx.x * 2 + r] * K3);
        const float4* s = (const float4*)bih;
        for (int i = tid; i < K3 / 4; i += 256) g[i] = s[i];
      }
    } else if (blockIdx.z == 0 && blockIdx.x >= 8) {
#pragma unroll
      for (int r = 0; r < 2; ++r) {
        float4* g = (float4*)(GHCP + (size_t)sxd[(blockIdx.x - 8) * 2 + r] * K3);
        const float4* s = (const float4*)bhh;
        for (int i = tid; i < K3 / 4; i += 256) g[i] = s[i];
      }
    }
  }
  int tx = tid & 15, ty = tid >> 4;
  int ar = tid & 31, ak = (tid >> 5) * 2;
  int li = tid & 63, lk = (tid >> 6) * 4;
  float acc[2][4] = {{0.f,0.f,0.f,0.f},{0.f,0.f,0.f,0.f}};
  const float* Arow = PAIR + (size_t)sxd[ar] * E + kbeg;
  int n = nBase + li;
  const float* Wrow = (n < 1512) ? (Gbig + (size_t)n * E + kbeg) : nullptr;
  float2 av = *(const float2*)(Arow + ak);
  float4 wv = Wrow ? *(const float4*)(Wrow + lk) : make_float4(0.f, 0.f, 0.f, 0.f);
  for (int k0 = 0; k0 < 256; k0 += 16) {
    As[ak + 0][ar] = av.x; As[ak + 1][ar] = av.y;
    Ws[lk + 0][li] = wv.x; Ws[lk + 1][li] = wv.y;
    Ws[lk + 2][li] = wv.z; Ws[lk + 3][li] = wv.w;
    __syncthreads();
    if (k0 + 16 < 256) {
      av = *(const float2*)(Arow + k0 + 16 + ak);
      wv = Wrow ? *(const float4*)(Wrow + k0 + 16 + lk) : make_float4(0.f, 0.f, 0.f, 0.f);
    }
    TILE_FMA32
    __syncthreads();
  }
#pragma unroll
  for (int r = 0; r < 2; ++r) {
    int mm = mBase + ty * 2 + r;
#pragma unroll
    for (int c = 0; c < 4; ++c) {
      int nn = nBase + tx * 4 + c;
      if (nn < 1512) atomicAdd(&SCT[(size_t)mm * K3 + nn], acc[r][c]);
    }
  }
}

// ---------- softmax/entropy + A2 build + SCT re-init (zeros) + fan-in counter reset ----
__global__ __launch_bounds__(256) void k_sm(float* __restrict__ SCT,
                                            const float* __restrict__ PAIR,
                                            const int* __restrict__ xdst,
                                            const float* __restrict__ v12,
                                            const float* __restrict__ bw,
                                            const float* __restrict__ c0s,
                                            float* __restrict__ outp,
                                            float* __restrict__ A2,
                                            const float* __restrict__ gb,
                                            int* __restrict__ cnt,
                                            int t, int finalMode) {
  __shared__ float sb[256];
  __shared__ float sb2[256];
  __shared__ float sps[E];
  int b = blockIdx.x, tid = threadIdx.x;
  if (!finalMode && b == 0 && tid < 32) cnt[tid] = 0;  // giup fan-in counters
  float* row = SCT + (size_t)b * K3;
  int xr = xdst[b];
  const float* sp = PAIR + (size_t)xr * E;
  for (int i = tid; i < E; i += 256) sps[i] = sp[i];
  __syncthreads();
  // bilinear self-score (Mqk part in cols 1000..1511) + SP.bw shift, one paired reduce
  float part = 0.f, pbw = 0.f;
  for (int i = tid; i < E; i += 256) {
    part += sps[i] * (row[1000 + i] + v12[i]);
    pbw += sps[i] * bw[i];
  }
  float ps, pb;
  brsum2(part, pbw, sb, sb2, &ps, &pb);
  float last = (ps + c0s[0]) * SCALE;
  float shift = pb + c0s[0];
  float s[4];
  float ml = last;
#pragma unroll
  for (int q = 0; q < 4; ++q) {
    int j = tid + q * 256;
    s[q] = (j < 1000) ? (row[j] + gb[j] + shift) * SCALE : -1e30f;
    ml = fmaxf(ml, s[q]);
  }
  float mx = brmax(ml, sb);
  float zp = 0.f, s1p = 0.f;
#pragma unroll
  for (int q = 0; q < 4; ++q) {
    int j = tid + q * 256;
    if (j < 1000) { float e = expf(s[q] - mx); zp += e; s1p += e * s[q]; }
  }
  if (tid == 0) { float e = expf(last - mx); zp += e; s1p += e * last; }
  float z, s1;
  brsum2(zp, s1p, sb, sb2, &z, &s1);
  if (tid == 0) outp[NS + b * 16 + t] = mx + logf(z) - s1 / z;
  if (!finalMode) {
    float inv = 1.f / z;
    float* a = A2 + (size_t)b * K3;
#pragma unroll
    for (int q = 0; q < 4; ++q) {
      int j = tid + q * 256;
      if (j < 1000) a[j] = expf(s[q] - mx) * inv;
    }
    if (tid < 24) a[1000 + tid] = 0.f;
    float pr = expf(last - mx) * inv;
    for (int i = tid; i < E; i += 256) a[1024 + i] = pr * sps[i];
    // re-init SCT row to zeros for the next step's split-K accumulation
    for (int n2 = tid; n2 < 1512; n2 += 256) row[n2] = 0.f;
  } else {
    float* so = outp + (size_t)b * (R + 1);
#pragma unroll
    for (int q = 0; q < 4; ++q) {
      int j = tid + q * 256;
      if (j < 1000) so[j] = s[q];
    }
    if (tid == 0) so[R] = last;
  }
}

// ---------- fused merged+GI gemm, split-K atomic, 32-row tiles, reg-prefetch,
// sharded h1 fan-in: grid (24,4,4) ----------
// Fan-in group (y,g): contributors x in {g,g+8,g+16} (cover GI cols e,512+e,1024+e for
// e in [g*64,g*64+64)) x 4 z-slices = 12 blocks for batch rows [y*32,y*32+32).
// 12th arriver computes H1P[xdst[b]][e] for its 32x64 shard (8 elems/thread, L2-hot).
__global__ __launch_bounds__(256) void k_giup(const float* __restrict__ A2,
                                              const float* __restrict__ Wbig,
                                              float* __restrict__ GI,
                                              const int* __restrict__ xdst,
                                              const float* __restrict__ bhh,
                                              float* __restrict__ H1P,
                                              int* __restrict__ cnt) {
  __shared__ float As[16][32];
  __shared__ float Ws[16][64];
  __shared__ int lastFlag;
  int tid = threadIdx.x;
  int nBase = blockIdx.x * 64;
  int mBase = blockIdx.y * 32;
  int kbeg = blockIdx.z * 384;
  int kend = kbeg + 384;
  int tx = tid & 15, ty = tid >> 4;
  int ar = tid & 31, ak = (tid >> 5) * 2;
  int li = tid & 63, wr = tid >> 6;
  float acc[2][4] = {{0.f,0.f,0.f,0.f},{0.f,0.f,0.f,0.f}};
  const float* Arow = A2 + (size_t)(mBase + ar) * K3;
  float2 av = *(const float2*)(Arow + kbeg + ak);
  float w0 = Wbig[(size_t)(kbeg + wr * 4 + 0) * K3 + nBase + li];
  float w1 = Wbig[(size_t)(kbeg + wr * 4 + 1) * K3 + nBase + li];
  float w2 = Wbig[(size_t)(kbeg + wr * 4 + 2) * K3 + nBase + li];
  float w3 = Wbig[(size_t)(kbeg + wr * 4 + 3) * K3 + nBase + li];
  for (int k0 = kbeg; k0 < kend; k0 += 16) {
    As[ak + 0][ar] = av.x; As[ak + 1][ar] = av.y;
    Ws[wr * 4 + 0][li] = w0; Ws[wr * 4 + 1][li] = w1;
    Ws[wr * 4 + 2][li] = w2; Ws[wr * 4 + 3][li] = w3;
    __syncthreads();
    if (k0 + 16 < kend) {  // register prefetch of next tile
      av = *(const float2*)(Arow + k0 + 16 + ak);
      w0 = Wbig[(size_t)(k0 + 16 + wr * 4 + 0) * K3 + nBase + li];
      w1 = Wbig[(size_t)(k0 + 16 + wr * 4 + 1) * K3 + nBase + li];
      w2 = Wbig[(size_t)(k0 + 16 + wr * 4 + 2) * K3 + nBase + li];
      w3 = Wbig[(size_t)(k0 + 16 + wr * 4 + 3) * K3 + nBase + li];
    }
    TILE_FMA32
    __syncthreads();
  }
#pragma unroll
  for (int r = 0; r < 2; ++r) {
    int mm = mBase + ty * 2 + r;
    size_t crow = (size_t)xdst[mm] * K3;
#pragma unroll
    for (int c = 0; c < 4; ++c) {
      int nn = nBase + tx * 4 + c;
      atomicAdd(&GI[crow + nn], acc[r][c]);
    }
  }
  __syncthreads();  // drains vmcnt: this block's GI atomics complete
  int g = blockIdx.x & 7;
  int ci = blockIdx.y * 8 + g;
  if (tid == 0) {
    int old = __hip_atomic_fetch_add(&cnt[ci], 1, __ATOMIC_ACQ_REL, __HIP_MEMORY_SCOPE_AGENT);
    lastFlag = (old == 11) ? 1 : 0;
  }
  __syncthreads();
  if (lastFlag) {
    int yB = blockIdx.y * 32;
    for (int i = tid; i < 32 * 64; i += 256) {
      int b = yB + (i >> 6);
      int e = g * 64 + (i & 63);
      const float* gi = GI + (size_t)xdst[b] * K3;
      float v0 = __hip_atomic_load(&gi[e], __ATOMIC_RELAXED, __HIP_MEMORY_SCOPE_AGENT);
      float v1 = __hip_atomic_load(&gi[E + e], __ATOMIC_RELAXED, __HIP_MEMORY_SCOPE_AGENT);
      float v2 = __hip_atomic_load(&gi[2 * E + e], __ATOMIC_RELAXED, __HIP_MEMORY_SCOPE_AGENT);
      float r = sigm(v0 + bhh[e]);
      float z = sigm(v1 + bhh[E + e]);
      H1P[(size_t)xdst[b] * E + e] = (1.f - z) * tanhf(v2 + r * bhh[2 * E + e]);
    }
  }
}

extern "C" void kernel_launch(void* const* d_in, const int* in_sizes, int n_in,
                              void* d_out, int out_size, void* d_ws, size_t ws_size,
                              hipStream_t stream) {
  (void)in_sizes; (void)n_in; (void)out_size; (void)ws_size;
  const int* tokens = (const int*)d_in[0];
  const float* emb = (const float*)d_in[1];
  const float* W_ih = (const float*)d_in[2];
  const float* W_hh = (const float*)d_in[3];
  const float* b_ih = (const float*)d_in[4];
  const float* b_hh = (const float*)d_in[5];
  const float* w_fc = (const float*)d_in[6];
  const float* b_fc = (const float*)d_in[7];
  const float* Wq = (const float*)d_in[8];
  const float* bq = (const float*)d_in[9];
  const float* Wk = (const float*)d_in[10];
  const float* bk = (const float*)d_in[11];
  float* out = (float*)d_out;

  float* ws = (float*)d_ws;
  size_t o = 0;
  float* GI = ws + o;    o += (size_t)B * S * K3;
  float* GHCP = ws + o;  o += (size_t)B * S * K3;   // position-keyed W_hh@h1 cache
  float* H1P = ws + o;   o += (size_t)B * S * E;    // position-keyed h1 cache
  float* PAIR = ws + o;  o += (size_t)B * S * E;
  float* Wbig = ws + o;  o += (size_t)K3 * K3;      // [EW(1000) | 0(24) | W_ih^T(512)] k-major
  float* Gbig = ws + o;  o += (size_t)1512 * E;     // [G2(1000) ; Mqk(512)]
  float* H1V = ws + o;   o += (size_t)1024 * E;     // vocab h1 table
  float* GHCV = ws + o;  o += (size_t)1024 * K3;    // vocab W_hh@h1 table (+bhh)
  float* SCT = ws + o;   o += (size_t)B * K3;
  float* A2 = ws + o;    o += (size_t)B * K3;
  float* gb = ws + o;    o += 1024;
  float* v12 = ws + o;   o += 512;
  float* bw = ws + o;    o += 512;
  float* wv3 = ws + o;   o += 512;
  float* c0s = ws + o;   o += 16;
  float* SCR = ws + o;   o += B * 16;
  int* pos0 = (int*)(ws + o); o += B * 16;
  int* pos1 = (int*)(ws + o); o += B * 16;
  int* wlb = (int*)(ws + o);  o += NW0;
  int* wlL = (int*)(ws + o);  o += NW0;
  int* wlR = (int*)(ws + o);  o += NW0;
  int* xdst = (int*)(ws + o); o += B;
  int* cnt = (int*)(ws + o);  o += 32;

  // ---- setup: 5 launches ----
  k_prep<<<279, 256, 0, stream>>>(Wq, Wk, W_ih, Wbig, pos0, wlb, wlL, wlR, out,
                                  Gbig, bq, bk, v12, bw, wv3, c0s);
  k_gemmD<<<dim3(32, 16), 256, 0, stream>>>(emb, E, R, W_ih, K3, nullptr, Wbig, K3,
                                            Gbig + (size_t)1000 * E, 512, Gbig, E, E);
  k_setupB<<<1000 + B * S + 8 + 4, 256, 0, stream>>>(tokens, Wbig, b_ih, b_hh, emb,
                                                     wv3, GI, H1V, SCT, gb);
  k_gemm<<<dim3(24, 16), 256, 0, stream>>>(H1V, E, 1000, W_hh, K3, E, b_hh, 1.f,
                                           GHCV, K3);
  k_pairc0<<<NW0, 256, 0, stream>>>(tokens, GI, GHCV, H1V, w_fc, b_fc, PAIR, SCR,
                                    H1P, GHCP);

  // ---- 14 merge steps, 5 kernels each (h1 fan-in sharded inside giup) ----
  for (int t = 0; t < 14; ++t) {
    int* pin = (t & 1) ? pos1 : pos0;
    int* pout = (t & 1) ? pos0 : pos1;
    k_qscsel<<<dim3(24, 4, 2), 256, 0, stream>>>(PAIR, SCR, pin, pout, wlb, wlL, wlR,
                                                 xdst, Gbig, SCT, GI, b_ih, GHCP, b_hh,
                                                 15 - t, 0);
    k_sm<<<B, 256, 0, stream>>>(SCT, PAIR, xdst, v12, bw, c0s, out, A2, gb, cnt, t, 0);
    k_giup<<<dim3(24, 4, 4), 256, 0, stream>>>(A2, Wbig, GI, xdst, b_hh, H1P, cnt);
    k_ghcs<<<dim3(24, 4, 2), 256, 0, stream>>>(xdst, H1P, W_hh, GHCP);
    k_pairc<<<NWS, 256, 0, stream>>>(wlb, wlL, wlR, GI, GHCP, H1P, w_fc, b_fc, PAIR, SCR);
  }

  // ---- final: h2 = PAIR[b][pos0[b*16]]; attention, scores+loss straight to out ----
  k_qscsel<<<dim3(24, 4, 2), 256, 0, stream>>>(PAIR, SCR, pos0, pos1, wlb, wlL, wlR,
                                               xdst, Gbig, SCT, GI, b_ih, GHCP, b_hh,
                                               1, 1);
  k_sm<<<B, 256, 0, stream>>>(SCT, PAIR, xdst, v12, bw, c0s, out, A2, gb, cnt, 15, 1);
}

// Round 17
// 1324.206 us; speedup vs baseline: 1.0526x; 1.0526x over previous
//
#include <hip/hip_runtime.h>

#define B 128
#define S 16
#define E 512
#define R 1000
#define K3 1536
#define NW0 1920   // init worklist: 128 b * 15 pairs
#define NWS 256    // per-step worklist: 128 b * 2 entries
#define NS (B * (R + 1))
#define SCALE 0.04419417382415922f

static __device__ __forceinline__ float sigm(float x) { return 1.f / (1.f + expf(-x)); }

// ---------- block reductions (256 threads) ----------
static __device__ __forceinline__ float brsum(float v, float* sb) {
  int tid = threadIdx.x;
  sb[tid] = v; __syncthreads();
  for (int s = 128; s > 0; s >>= 1) {
    if (tid < s) sb[tid] += sb[tid + s];
    __syncthreads();
  }
  float r = sb[0]; __syncthreads();
  return r;
}
static __device__ __forceinline__ float brmax(float v, float* sb) {
  int tid = threadIdx.x;
  sb[tid] = v; __syncthreads();
  for (int s = 128; s > 0; s >>= 1) {
    if (tid < s) sb[tid] = fmaxf(sb[tid], sb[tid + s]);
    __syncthreads();
  }
  float r = sb[0]; __syncthreads();
  return r;
}
// paired sum reduction: (v1,v2) -> (sb[0], sb2[0])
static __device__ __forceinline__ void brsum2(float v1, float v2, float* sb, float* sb2,
                                              float* o1, float* o2) {
  int tid = threadIdx.x;
  sb[tid] = v1; sb2[tid] = v2; __syncthreads();
  for (int s = 128; s > 0; s >>= 1) {
    if (tid < s) { sb[tid] += sb[tid + s]; sb2[tid] += sb2[tid + s]; }
    __syncthreads();
  }
  *o1 = sb[0]; *o2 = sb2[0]; __syncthreads();
}

#define TILE_FMA \
  _Pragma("unroll") \
  for (int k = 0; k < 16; ++k) { \
    float4 a4 = *(const float4*)&As[k][ty * 4]; \
    float4 w4 = *(const float4*)&Ws[k][tx * 4]; \
    acc[0][0] = fmaf(a4.x, w4.x, acc[0][0]); acc[0][1] = fmaf(a4.x, w4.y, acc[0][1]); \
    acc[0][2] = fmaf(a4.x, w4.z, acc[0][2]); acc[0][3] = fmaf(a4.x, w4.w, acc[0][3]); \
    acc[1][0] = fmaf(a4.y, w4.x, acc[1][0]); acc[1][1] = fmaf(a4.y, w4.y, acc[1][1]); \
    acc[1][2] = fmaf(a4.y, w4.z, acc[1][2]); acc[1][3] = fmaf(a4.y, w4.w, acc[1][3]); \
    acc[2][0] = fmaf(a4.z, w4.x, acc[2][0]); acc[2][1] = fmaf(a4.z, w4.y, acc[2][1]); \
    acc[2][2] = fmaf(a4.z, w4.z, acc[2][2]); acc[2][3] = fmaf(a4.z, w4.w, acc[2][3]); \
    acc[3][0] = fmaf(a4.w, w4.x, acc[3][0]); acc[3][1] = fmaf(a4.w, w4.y, acc[3][1]); \
    acc[3][2] = fmaf(a4.w, w4.z, acc[3][2]); acc[3][3] = fmaf(a4.w, w4.w, acc[3][3]); \
  }

// 32-row-tile inner product: acc[2][4], A in As[16][32], W in Ws[16][64]
#define TILE_FMA32 \
  _Pragma("unroll") \
  for (int k = 0; k < 16; ++k) { \
    float2 a2 = *(const float2*)&As[k][ty * 2]; \
    float4 w4 = *(const float4*)&Ws[k][tx * 4]; \
    acc[0][0] = fmaf(a2.x, w4.x, acc[0][0]); acc[0][1] = fmaf(a2.x, w4.y, acc[0][1]); \
    acc[0][2] = fmaf(a2.x, w4.z, acc[0][2]); acc[0][3] = fmaf(a2.x, w4.w, acc[0][3]); \
    acc[1][0] = fmaf(a2.y, w4.x, acc[1][0]); acc[1][1] = fmaf(a2.y, w4.y, acc[1][1]); \
    acc[1][2] = fmaf(a2.y, w4.z, acc[1][2]); acc[1][3] = fmaf(a2.y, w4.w, acc[1][3]); \
  }

// ---------- generic tiled gemm (standalone body — VGPR~44 codegen) ----------
__global__ __launch_bounds__(256) void k_gemm(const float* __restrict__ A, int lda, int M,
                                              const float* __restrict__ W, int N, int K,
                                              const float* __restrict__ bias, float scale,
                                              float* __restrict__ C, int ldc) {
  __shared__ float As[16][64];
  __shared__ float Ws[16][64];
  int tid = threadIdx.x;
  int mBase = blockIdx.y * 64;
  int nBase = blockIdx.x * 64;
  int tx = tid & 15, ty = tid >> 4;
  int li = tid & 63;
  int lk = (tid >> 6) * 4;
  float acc[4][4] = {{0.f,0.f,0.f,0.f},{0.f,0.f,0.f,0.f},{0.f,0.f,0.f,0.f},{0.f,0.f,0.f,0.f}};
  int m = mBase + li;
  const float* Arow = (m < M) ? (A + (size_t)m * lda) : nullptr;
  int n = nBase + li;
  const float* Wrow = (n < N) ? (W + (size_t)n * K) : nullptr;

  float4 av = Arow ? *(const float4*)(Arow + lk) : make_float4(0.f, 0.f, 0.f, 0.f);
  float4 wv = Wrow ? *(const float4*)(Wrow + lk) : make_float4(0.f, 0.f, 0.f, 0.f);

  for (int k0 = 0; k0 < K; k0 += 16) {
    As[lk + 0][li] = av.x; As[lk + 1][li] = av.y;
    As[lk + 2][li] = av.z; As[lk + 3][li] = av.w;
    Ws[lk + 0][li] = wv.x; Ws[lk + 1][li] = wv.y;
    Ws[lk + 2][li] = wv.z; Ws[lk + 3][li] = wv.w;
    __syncthreads();
    if (k0 + 16 < K) {
      av = Arow ? *(const float4*)(Arow + k0 + 16 + lk) : make_float4(0.f, 0.f, 0.f, 0.f);
      wv = Wrow ? *(const float4*)(Wrow + k0 + 16 + lk) : make_float4(0.f, 0.f, 0.f, 0.f);
    }
    TILE_FMA
    __syncthreads();
  }
#pragma unroll
  for (int r = 0; r < 4; ++r) {
    int mm = mBase + ty * 4 + r;
    if (mm >= M) continue;
#pragma unroll
    for (int c = 0; c < 4; ++c) {
      int nn = nBase + tx * 4 + c;
      if (nn >= N) continue;
      float v = acc[r][c] * scale;
      if (bias) v += bias[nn];
      C[(size_t)mm * ldc + nn] = v;
    }
  }
}

// ---------- dual-output gemm: n<N1 -> W1,C1 ; else W2,C2 ----------
__global__ __launch_bounds__(256) void k_gemmD(const float* __restrict__ A, int lda, int M,
                                               const float* __restrict__ W1, int N1,
                                               const float* __restrict__ b1,
                                               float* __restrict__ C1, int ldc1,
                                               const float* __restrict__ W2, int N2,
                                               float* __restrict__ C2, int ldc2, int K) {
  __shared__ float As[16][64];
  __shared__ float Ws[16][64];
  int tid = threadIdx.x;
  int mBase = blockIdx.y * 64;
  int nBase = blockIdx.x * 64;
  int tx = tid & 15, ty = tid >> 4;
  int li = tid & 63;
  int lk = (tid >> 6) * 4;
  float acc[4][4] = {{0.f,0.f,0.f,0.f},{0.f,0.f,0.f,0.f},{0.f,0.f,0.f,0.f},{0.f,0.f,0.f,0.f}};
  int m = mBase + li;
  const float* Arow = (m < M) ? (A + (size_t)m * lda) : nullptr;
  int n = nBase + li;
  const float* Wrow = nullptr;
  if (n < N1) Wrow = W1 + (size_t)n * K;
  else if (n < N1 + N2) Wrow = W2 + (size_t)(n - N1) * K;

  float4 av = Arow ? *(const float4*)(Arow + lk) : make_float4(0.f, 0.f, 0.f, 0.f);
  float4 wv = Wrow ? *(const float4*)(Wrow + lk) : make_float4(0.f, 0.f, 0.f, 0.f);

  for (int k0 = 0; k0 < K; k0 += 16) {
    As[lk + 0][li] = av.x; As[lk + 1][li] = av.y;
    As[lk + 2][li] = av.z; As[lk + 3][li] = av.w;
    Ws[lk + 0][li] = wv.x; Ws[lk + 1][li] = wv.y;
    Ws[lk + 2][li] = wv.z; Ws[lk + 3][li] = wv.w;
    __syncthreads();
    if (k0 + 16 < K) {
      av = Arow ? *(const float4*)(Arow + k0 + 16 + lk) : make_float4(0.f, 0.f, 0.f, 0.f);
      wv = Wrow ? *(const float4*)(Wrow + k0 + 16 + lk) : make_float4(0.f, 0.f, 0.f, 0.f);
    }
    TILE_FMA
    __syncthreads();
  }
#pragma unroll
  for (int r = 0; r < 4; ++r) {
    int mm = mBase + ty * 4 + r;
    if (mm >= M) continue;
#pragma unroll
    for (int c = 0; c < 4; ++c) {
      int nn = nBase + tx * 4 + c;
      if (nn < N1) {
        float v = acc[r][c];
        if (b1) v += b1[nn];
        C1[(size_t)mm * ldc1 + nn] = v;
      } else if (nn < N1 + N2) {
        C2[(size_t)mm * ldc2 + (nn - N1)] = acc[r][c];
      }
    }
  }
}

// ---------- 64x64 transpose tile (device) ----------
static __device__ void dev_tr64(float (*t)[65], int tid, const float* __restrict__ src,
                                int Cc, float* __restrict__ dst, int ldd, int bx, int by) {
  int tx = tid & 15, ty = tid >> 4;
  int rb = by * 64, cb = bx * 64;
#pragma unroll
  for (int i = 0; i < 4; ++i) {
    int r = rb + ty + i * 16;
    float4 v = *(const float4*)(src + (size_t)r * Cc + cb + tx * 4);
    t[ty + i * 16][tx * 4 + 0] = v.x; t[ty + i * 16][tx * 4 + 1] = v.y;
    t[ty + i * 16][tx * 4 + 2] = v.z; t[ty + i * 16][tx * 4 + 3] = v.w;
  }
  __syncthreads();
#pragma unroll
  for (int i = 0; i < 4; ++i) {
    int c = cb + ty + i * 16;
    float4 v;
    v.x = t[tx * 4 + 0][ty + i * 16]; v.y = t[tx * 4 + 1][ty + i * 16];
    v.z = t[tx * 4 + 2][ty + i * 16]; v.w = t[tx * 4 + 3][ty + i * 16];
    *(float4*)(dst + (size_t)c * ldd + rb + tx * 4) = v;
  }
}

// ---------- setup L1: Wih transpose + initwl + pad + out14 + Mqk NT-gemm + v12/bw/wv3/c0 ----
__global__ __launch_bounds__(256) void k_prep(const float* __restrict__ Wq,
                                              const float* __restrict__ Wk,
                                              const float* __restrict__ Wih,
                                              float* __restrict__ Wbig,
                                              int* __restrict__ pos,
                                              int* __restrict__ wlb,
                                              int* __restrict__ wlL,
                                              int* __restrict__ wlR,
                                              float* __restrict__ outp,
                                              float* __restrict__ Gbig,
                                              const float* __restrict__ bq,
                                              const float* __restrict__ bk,
                                              float* __restrict__ v12,
                                              float* __restrict__ bw,
                                              float* __restrict__ wv3,
                                              float* __restrict__ c0s) {
  __shared__ float t[64][65];
  int blk = blockIdx.x, tid = threadIdx.x;
  if (blk < 192) {
    dev_tr64(t, tid, Wih, E, Wbig + (size_t)1024 * K3, K3, blk & 7, blk >> 3);
  } else if (blk < 200) {
    int idx = (blk - 192) * 256 + tid;
    if (idx < B * 16) pos[idx] = idx & 15;
    if (idx < NW0) {
      wlb[idx] = idx / 15;
      int i = idx % 15;
      wlL[idx] = i;
      wlR[idx] = i + 1;
    }
    if (idx < B) outp[NS + idx * 16 + 14] = 0.f;  // loss col 14 is identically 0
  } else if (blk < 208) {
    int idx = (blk - 200) * 256 + tid;
    for (int i = idx; i < 24 * K3; i += 8 * 256) Wbig[(size_t)1000 * K3 + i] = 0.f;
  } else if (blk < 272) {
    // Mqk[i,f] = sum_e Wq[e,i]*Wk[e,f]  (NT gemm, no transposes needed)
    int j = blk - 208;
    int fT = (j & 7) * 64, iT = (j >> 3) * 64;
    float (*As)[64] = (float(*)[64])&t[0][0];
    float (*Ws)[64] = (float(*)[64])&t[20][0];
    int tx = tid & 15, ty = tid >> 4;
    int li = tid & 63, lk = (tid >> 6) * 4;
    float acc[4][4] = {{0.f,0.f,0.f,0.f},{0.f,0.f,0.f,0.f},{0.f,0.f,0.f,0.f},{0.f,0.f,0.f,0.f}};
    float a0 = Wq[(size_t)(lk + 0) * E + iT + li];
    float a1 = Wq[(size_t)(lk + 1) * E + iT + li];
    float a2 = Wq[(size_t)(lk + 2) * E + iT + li];
    float a3 = Wq[(size_t)(lk + 3) * E + iT + li];
    float w0 = Wk[(size_t)(lk + 0) * E + fT + li];
    float w1 = Wk[(size_t)(lk + 1) * E + fT + li];
    float w2 = Wk[(size_t)(lk + 2) * E + fT + li];
    float w3 = Wk[(size_t)(lk + 3) * E + fT + li];
    for (int e0 = 0; e0 < E; e0 += 16) {
      As[lk + 0][li] = a0; As[lk + 1][li] = a1;
      As[lk + 2][li] = a2; As[lk + 3][li] = a3;
      Ws[lk + 0][li] = w0; Ws[lk + 1][li] = w1;
      Ws[lk + 2][li] = w2; Ws[lk + 3][li] = w3;
      __syncthreads();
      if (e0 + 16 < E) {
        a0 = Wq[(size_t)(e0 + 16 + lk + 0) * E + iT + li];
        a1 = Wq[(size_t)(e0 + 16 + lk + 1) * E + iT + li];
        a2 = Wq[(size_t)(e0 + 16 + lk + 2) * E + iT + li];
        a3 = Wq[(size_t)(e0 + 16 + lk + 3) * E + iT + li];
        w0 = Wk[(size_t)(e0 + 16 + lk + 0) * E + fT + li];
        w1 = Wk[(size_t)(e0 + 16 + lk + 1) * E + fT + li];
        w2 = Wk[(size_t)(e0 + 16 + lk + 2) * E + fT + li];
        w3 = Wk[(size_t)(e0 + 16 + lk + 3) * E + fT + li];
      }
      TILE_FMA
      __syncthreads();
    }
#pragma unroll
    for (int r = 0; r < 4; ++r)
#pragma unroll
      for (int c = 0; c < 4; ++c)
        Gbig[(size_t)(1000 + iT + ty * 4 + r) * E + fT + tx * 4 + c] = acc[r][c];
  } else if (blk < 274) {
    int i = (blk - 272) * 256 + tid;
    float s = 0.f;
    for (int e = 0; e < E; ++e) s += Wq[(size_t)e * E + i] * bk[e] + bq[e] * Wk[(size_t)e * E + i];
    v12[i] = s;
  } else if (blk < 276) {
    int i = (blk - 274) * 256 + tid;
    float s = 0.f;
    for (int e = 0; e < E; ++e) s += bk[e] * Wq[(size_t)e * E + i];
    bw[i] = s;
  } else if (blk < 278) {
    int f = (blk - 276) * 256 + tid;
    float s = 0.f;
    for (int e = 0; e < E; ++e) s += bq[e] * Wk[(size_t)e * E + f];
    wv3[f] = s;
  } else {
    float* sb = &t[0][0];
    float p = 0.f;
    for (int e = tid; e < E; e += 256) p += bq[e] * bk[e];
    float s = brsum(p, sb);
    if (tid == 0) c0s[0] = s;
  }
}

// ---------- setup B: H1V vocab h1 [0,1000) | GI gather [1000,3048) | SCT zero | gb ----------
__global__ __launch_bounds__(256) void k_setupB(const int* __restrict__ tokens,
                                                const float* __restrict__ Wbig,
                                                const float* __restrict__ bih,
                                                const float* __restrict__ bhh,
                                                const float* __restrict__ emb,
                                                const float* __restrict__ wv3,
                                                float* __restrict__ GI,
                                                float* __restrict__ H1V,
                                                float* __restrict__ SCT,
                                                float* __restrict__ gb) {
  int blk = blockIdx.x, tid = threadIdx.x;
  if (blk < 1000) {
    const float* ew = Wbig + (size_t)blk * K3;
    float* h = H1V + (size_t)blk * E;
    for (int e = tid; e < E; e += 256) {
      float g0 = ew[e] + bih[e];
      float g1 = ew[E + e] + bih[E + e];
      float g2 = ew[2 * E + e] + bih[2 * E + e];
      float r = sigm(g0 + bhh[e]);
      float z = sigm(g1 + bhh[E + e]);
      h[e] = (1.f - z) * tanhf(g2 + r * bhh[2 * E + e]);
    }
  } else if (blk < 1000 + B * S) {
    int p = blk - 1000;
    int tok = tokens[p];
    const float4* src = (const float4*)(Wbig + (size_t)tok * K3);
    const float4* bv = (const float4*)bih;
    float4* dst = (float4*)(GI + (size_t)p * K3);
    for (int i = tid; i < K3 / 4; i += 256) {
      float4 a = src[i], b = bv[i];
      dst[i] = make_float4(a.x + b.x, a.y + b.y, a.z + b.z, a.w + b.w);
    }
  } else if (blk < 1000 + B * S + 8) {
    int rb = blk - (1000 + B * S);
    for (int m = rb * 16; m < rb * 16 + 16; ++m) {
      float* r = SCT + (size_t)m * K3;
      for (int n = tid; n < 1512; n += 256) r[n] = 0.f;
    }
  } else {
    int r = (blk - (1000 + B * S + 8)) * 256 + tid;
    if (r < R) {
      const float* er = emb + (size_t)r * E;
      float s = 0.f;
      for (int f = 0; f < E; ++f) s += er[f] * wv3[f];
      gb[r] = s;  // raw: score adds (gb + SP.bw + c0)
    }
  }
}

// ---------- setup pairc: compute PAIR/SCR from vocab tables + gather position caches ----
__global__ __launch_bounds__(256) void k_pairc0(const int* __restrict__ tokens,
                                                const float* __restrict__ GI,
                                                const float* __restrict__ GHCV,
                                                const float* __restrict__ H1V,
                                                const float* __restrict__ wfc,
                                                const float* __restrict__ bfc,
                                                float* __restrict__ PAIR,
                                                float* __restrict__ SCR,
                                                float* __restrict__ H1P,
                                                float* __restrict__ GHCP) {
  __shared__ float sb[256];
  int w = blockIdx.x, tid = threadIdx.x;
  int b = w / 15, i = w % 15;
  int lp = b * 16 + i;
  int tok = tokens[lp];
  const float* gr = GI + (size_t)(lp + 1) * K3;
  const float* gh = GHCV + (size_t)tok * K3;
  const float* h = H1V + (size_t)tok * E;
  float* ghp = GHCP + (size_t)lp * K3;
  float* hp = H1P + (size_t)lp * E;
  float* p = PAIR + (size_t)lp * E;
  float part = 0.f;
  for (int e = tid; e < E; e += 256) {
    float g0 = gh[e], g1 = gh[E + e], g2 = gh[2 * E + e], he = h[e];
    ghp[e] = g0; ghp[E + e] = g1; ghp[2 * E + e] = g2; hp[e] = he;
    float r = sigm(gr[e] + g0);
    float z = sigm(gr[E + e] + g1);
    float n = tanhf(gr[2 * E + e] + r * g2);
    float pv = (1.f - z) * n + z * he;
    p[e] = pv;
    part += pv * wfc[e];
  }
  float d = brsum(part, sb);
  if (tid == 0) SCR[lp] = sigm(d + bfc[0]);
}

// ---------- per-step h1: one block per batch; recompute position xdst[b] ----------
__global__ __launch_bounds__(256) void k_h1c(const int* __restrict__ xdst,
                                             const float* __restrict__ GI,
                                             const float* __restrict__ bhh,
                                             float* __restrict__ H1P) {
  int p = xdst[blockIdx.x], tid = threadIdx.x;
  const float* gi = GI + (size_t)p * K3;
  float* h = H1P + (size_t)p * E;
  for (int e = tid; e < E; e += 256) {
    float r = sigm(gi[e] + bhh[e]);
    float z = sigm(gi[E + e] + bhh[E + e]);
    h[e] = (1.f - z) * tanhf(gi[2 * E + e] + r * bhh[2 * E + e]);
  }
}

// ---------- GHC split-K gemm, 32-row tiles, position-indirect: grid (24, 4, 2) ----------
__global__ __launch_bounds__(256) void k_ghcs(const int* __restrict__ xdst,
                                              const float* __restrict__ H1P,
                                              const float* __restrict__ Whh,
                                              float* __restrict__ GHCP) {
  __shared__ float As[16][32];
  __shared__ float Ws[16][64];
  __shared__ int sp[32];
  int tid = threadIdx.x;
  int nBase = blockIdx.x * 64;
  int mBase = blockIdx.y * 32;
  int kbeg = blockIdx.z * 256;
  if (tid < 32) sp[tid] = xdst[mBase + tid];
  __syncthreads();
  int tx = tid & 15, ty = tid >> 4;
  int ar = tid & 31, ak = (tid >> 5) * 2;
  int li = tid & 63, lk = (tid >> 6) * 4;
  float acc[2][4] = {{0.f,0.f,0.f,0.f},{0.f,0.f,0.f,0.f}};
  const float* Arow = H1P + (size_t)sp[ar] * E + kbeg;
  const float* Wrow = Whh + (size_t)(nBase + li) * E + kbeg;
  float2 av = *(const float2*)(Arow + ak);
  float4 wv = *(const float4*)(Wrow + lk);
  for (int k0 = 0; k0 < 256; k0 += 16) {
    As[ak + 0][ar] = av.x; As[ak + 1][ar] = av.y;
    Ws[lk + 0][li] = wv.x; Ws[lk + 1][li] = wv.y;
    Ws[lk + 2][li] = wv.z; Ws[lk + 3][li] = wv.w;
    __syncthreads();
    if (k0 + 16 < 256) {
      av = *(const float2*)(Arow + k0 + 16 + ak);
      wv = *(const float4*)(Wrow + k0 + 16 + lk);
    }
    TILE_FMA32
    __syncthreads();
  }
#pragma unroll
  for (int r = 0; r < 2; ++r) {
    size_t crow = (size_t)sp[ty * 2 + r] * K3;
#pragma unroll
    for (int c = 0; c < 4; ++c) {
      int nn = nBase + tx * 4 + c;
      atomicAdd(&GHCP[crow + nn], acc[r][c]);
    }
  }
}

// ---------- pair + fc score (position-keyed H1P/GHCP caches) ----------
__global__ __launch_bounds__(256) void k_pairc(const int* __restrict__ wlb,
                                               const int* __restrict__ wlL,
                                               const int* __restrict__ wlR,
                                               const float* __restrict__ GI,
                                               const float* __restrict__ GHCP,
                                               const float* __restrict__ H1P,
                                               const float* __restrict__ wfc,
                                               const float* __restrict__ bfc,
                                               float* __restrict__ PAIR,
                                               float* __restrict__ SCR) {
  __shared__ float sb[256];
  int w = blockIdx.x, tid = threadIdx.x;
  int b = wlb[w], ls = wlL[w], rs = wlR[w];
  int lp = b * 16 + ls;
  const float* gr = GI + (size_t)(b * 16 + rs) * K3;
  const float* gh = GHCP + (size_t)lp * K3;
  const float* h = H1P + (size_t)lp * E;
  float* p = PAIR + (size_t)lp * E;
  float part = 0.f;
  for (int e = tid; e < E; e += 256) {
    float r = sigm(gr[e] + gh[e]);
    float z = sigm(gr[E + e] + gh[E + e]);
    float n = tanhf(gr[2 * E + e] + r * gh[2 * E + e]);
    float pv = (1.f - z) * n + z * h[e];
    p[e] = pv;
    part += pv * wfc[e];
  }
  float d = brsum(part, sb);
  if (tid == 0) SCR[b * 16 + ls] = sigm(d + bfc[0]);
}

// ---------- fused sel + scores split-K gemm, 32-row tiles: grid (24, 4, 2) ----------
// Block (0, y, 0) writes pos/wl/xdst; z==1: x<16 write GI[xdst]=bih (2 rows each),
// x in [16,24) write GHCP[xdst]=bhh (4 rows each). float4 stores.
__global__ __launch_bounds__(256) void k_qscsel(const float* __restrict__ PAIR,
                                                const float* __restrict__ SCR,
                                                const int* __restrict__ pin,
                                                int* __restrict__ pout,
                                                int* __restrict__ wlb,
                                                int* __restrict__ wlL,
                                                int* __restrict__ wlR,
                                                int* __restrict__ xdst,
                                                const float* __restrict__ Gbig,
                                                float* __restrict__ SCT,
                                                float* __restrict__ GI,
                                                const float* __restrict__ bih,
                                                float* __restrict__ GHCP,
                                                const float* __restrict__ bhh,
                                                int P, int finalMode) {
  __shared__ float As[16][32];
  __shared__ float Ws[16][64];
  __shared__ int sxd[32];
  int tid = threadIdx.x;
  int nBase = blockIdx.x * 64;
  int mBase = blockIdx.y * 32;
  int kbeg = blockIdx.z * 256;
  if (tid < 32) {
    int b = mBase + tid;
    if (finalMode) {
      int xr = b * 16 + pin[b * 16];
      sxd[tid] = xr;
      if (blockIdx.x == 0 && blockIdx.z == 0) xdst[b] = xr;
    } else {
      int L = P + 1;
      int lp[16];
      for (int i = 0; i < L; ++i) lp[i] = pin[b * 16 + i];
      float best = -1e30f; int sel = 0;
      for (int i = 0; i < P; ++i) {
        float v = SCR[b * 16 + lp[i]];
        if (v > best) { best = v; sel = i; }
      }
      int r1i = (sel + 2 < L) ? sel + 2 : L - 1;
      int l1 = lp[sel], r1 = lp[r1i];
      int l0 = (sel > 0) ? lp[sel - 1] : l1;
      int r0 = (sel > 0) ? lp[sel] : r1;
      sxd[tid] = b * 16 + l1;
      if (blockIdx.x == 0 && blockIdx.z == 0) {
        wlb[2 * b] = b;     wlL[2 * b] = l0;     wlR[2 * b] = r0;
        wlb[2 * b + 1] = b; wlL[2 * b + 1] = l1; wlR[2 * b + 1] = r1;
        xdst[b] = b * 16 + l1;
        for (int i = 0; i < L - 1; ++i)
          pout[b * 16 + i] = (i <= sel) ? lp[i] : lp[i + 1];
      }
    }
  }
  __syncthreads();
  // Early cache-row inits, off the k_sm/k_h1c critical paths (duplicate-safe writes):
  // old GI[xdst]/GHCP[xdst] values have no readers after this point this step.
  if (!finalMode && blockIdx.z == 1) {
    if (blockIdx.x < 16) {
#pragma unroll
      for (int r = 0; r < 2; ++r) {
        float4* g = (float4*)(GI + (size_t)sxd[blockIdx.x * 2 + r] * K3);
        const float4* s = (const float4*)bih;
        for (int i = tid; i < K3 / 4; i += 256) g[i] = s[i];
      }
    } else {
#pragma unroll
      for (int r = 0; r < 4; ++r) {
        float4* g = (float4*)(GHCP + (size_t)sxd[(blockIdx.x - 16) * 4 + r] * K3);
        const float4* s = (const float4*)bhh;
        for (int i = tid; i < K3 / 4; i += 256) g[i] = s[i];
      }
    }
  }
  int tx = tid & 15, ty = tid >> 4;
  int ar = tid & 31, ak = (tid >> 5) * 2;
  int li = tid & 63, lk = (tid >> 6) * 4;
  float acc[2][4] = {{0.f,0.f,0.f,0.f},{0.f,0.f,0.f,0.f}};
  const float* Arow = PAIR + (size_t)sxd[ar] * E + kbeg;
  int n = nBase + li;
  const float* Wrow = (n < 1512) ? (Gbig + (size_t)n * E + kbeg) : nullptr;
  float2 av = *(const float2*)(Arow + ak);
  float4 wv = Wrow ? *(const float4*)(Wrow + lk) : make_float4(0.f, 0.f, 0.f, 0.f);
  for (int k0 = 0; k0 < 256; k0 += 16) {
    As[ak + 0][ar] = av.x; As[ak + 1][ar] = av.y;
    Ws[lk + 0][li] = wv.x; Ws[lk + 1][li] = wv.y;
    Ws[lk + 2][li] = wv.z; Ws[lk + 3][li] = wv.w;
    __syncthreads();
    if (k0 + 16 < 256) {
      av = *(const float2*)(Arow + k0 + 16 + ak);
      wv = Wrow ? *(const float4*)(Wrow + k0 + 16 + lk) : make_float4(0.f, 0.f, 0.f, 0.f);
    }
    TILE_FMA32
    __syncthreads();
  }
#pragma unroll
  for (int r = 0; r < 2; ++r) {
    int mm = mBase + ty * 2 + r;
#pragma unroll
    for (int c = 0; c < 4; ++c) {
      int nn = nBase + tx * 4 + c;
      if (nn < 1512) atomicAdd(&SCT[(size_t)mm * K3 + nn], acc[r][c]);
    }
  }
}

// ---------- softmax/entropy + A2 build + SCT re-init (zeros) ----------
// SCT holds RAW dots; score = (SCT + gb_raw + SP.bw + c0)*SCALE.
__global__ __launch_bounds__(256) void k_sm(float* __restrict__ SCT,
                                            const float* __restrict__ PAIR,
                                            const int* __restrict__ xdst,
                                            const float* __restrict__ v12,
                                            const float* __restrict__ bw,
                                            const float* __restrict__ c0s,
                                            float* __restrict__ outp,
                                            float* __restrict__ A2,
                                            const float* __restrict__ gb,
                                            int t, int finalMode) {
  __shared__ float sb[256];
  __shared__ float sb2[256];
  __shared__ float sps[E];
  int b = blockIdx.x, tid = threadIdx.x;
  float* row = SCT + (size_t)b * K3;
  int xr = xdst[b];
  const float* sp = PAIR + (size_t)xr * E;
  for (int i = tid; i < E; i += 256) sps[i] = sp[i];
  __syncthreads();
  // bilinear self-score (Mqk part in cols 1000..1511) + SP.bw shift, one paired reduce
  float part = 0.f, pbw = 0.f;
  for (int i = tid; i < E; i += 256) {
    part += sps[i] * (row[1000 + i] + v12[i]);
    pbw += sps[i] * bw[i];
  }
  float ps, pb;
  brsum2(part, pbw, sb, sb2, &ps, &pb);
  float last = (ps + c0s[0]) * SCALE;
  float shift = pb + c0s[0];
  float s[4];
  float ml = last;
#pragma unroll
  for (int q = 0; q < 4; ++q) {
    int j = tid + q * 256;
    s[q] = (j < 1000) ? (row[j] + gb[j] + shift) * SCALE : -1e30f;
    ml = fmaxf(ml, s[q]);
  }
  float mx = brmax(ml, sb);
  float zp = 0.f, s1p = 0.f;
#pragma unroll
  for (int q = 0; q < 4; ++q) {
    int j = tid + q * 256;
    if (j < 1000) { float e = expf(s[q] - mx); zp += e; s1p += e * s[q]; }
  }
  if (tid == 0) { float e = expf(last - mx); zp += e; s1p += e * last; }
  float z, s1;
  brsum2(zp, s1p, sb, sb2, &z, &s1);
  if (tid == 0) outp[NS + b * 16 + t] = mx + logf(z) - s1 / z;
  if (!finalMode) {
    float inv = 1.f / z;
    float* a = A2 + (size_t)b * K3;
#pragma unroll
    for (int q = 0; q < 4; ++q) {
      int j = tid + q * 256;
      if (j < 1000) a[j] = expf(s[q] - mx) * inv;
    }
    if (tid < 24) a[1000 + tid] = 0.f;
    float pr = expf(last - mx) * inv;
    for (int i = tid; i < E; i += 256) a[1024 + i] = pr * sps[i];
    // re-init SCT row to zeros for the next step's split-K accumulation
    for (int n2 = tid; n2 < 1512; n2 += 256) row[n2] = 0.f;
  } else {
    float* so = outp + (size_t)b * (R + 1);
#pragma unroll
    for (int q = 0; q < 4; ++q) {
      int j = tid + q * 256;
      if (j < 1000) so[j] = s[q];
    }
    if (tid == 0) so[R] = last;
  }
}

// ---------- fused merged+GI gemm, split-K atomic, 32-row tiles, reg-prefetch:
// grid (24,4,4) ----------
__global__ __launch_bounds__(256) void k_giup(const float* __restrict__ A2,
                                              const float* __restrict__ Wbig,
                                              float* __restrict__ GI,
                                              const int* __restrict__ xdst) {
  __shared__ float As[16][32];
  __shared__ float Ws[16][64];
  int tid = threadIdx.x;
  int nBase = blockIdx.x * 64;
  int mBase = blockIdx.y * 32;
  int kbeg = blockIdx.z * 384;
  int kend = kbeg + 384;
  int tx = tid & 15, ty = tid >> 4;
  int ar = tid & 31, ak = (tid >> 5) * 2;
  int li = tid & 63, wr = tid >> 6;
  float acc[2][4] = {{0.f,0.f,0.f,0.f},{0.f,0.f,0.f,0.f}};
  const float* Arow = A2 + (size_t)(mBase + ar) * K3;
  float2 av = *(const float2*)(Arow + kbeg + ak);
  float w0 = Wbig[(size_t)(kbeg + wr * 4 + 0) * K3 + nBase + li];
  float w1 = Wbig[(size_t)(kbeg + wr * 4 + 1) * K3 + nBase + li];
  float w2 = Wbig[(size_t)(kbeg + wr * 4 + 2) * K3 + nBase + li];
  float w3 = Wbig[(size_t)(kbeg + wr * 4 + 3) * K3 + nBase + li];
  for (int k0 = kbeg; k0 < kend; k0 += 16) {
    As[ak + 0][ar] = av.x; As[ak + 1][ar] = av.y;
    Ws[wr * 4 + 0][li] = w0; Ws[wr * 4 + 1][li] = w1;
    Ws[wr * 4 + 2][li] = w2; Ws[wr * 4 + 3][li] = w3;
    __syncthreads();
    if (k0 + 16 < kend) {  // register prefetch of next tile
      av = *(const float2*)(Arow + k0 + 16 + ak);
      w0 = Wbig[(size_t)(k0 + 16 + wr * 4 + 0) * K3 + nBase + li];
      w1 = Wbig[(size_t)(k0 + 16 + wr * 4 + 1) * K3 + nBase + li];
      w2 = Wbig[(size_t)(k0 + 16 + wr * 4 + 2) * K3 + nBase + li];
      w3 = Wbig[(size_t)(k0 + 16 + wr * 4 + 3) * K3 + nBase + li];
    }
    TILE_FMA32
    __syncthreads();
  }
#pragma unroll
  for (int r = 0; r < 2; ++r) {
    int mm = mBase + ty * 2 + r;
    size_t crow = (size_t)xdst[mm] * K3;
#pragma unroll
    for (int c = 0; c < 4; ++c) {
      int nn = nBase + tx * 4 + c;
      atomicAdd(&GI[crow + nn], acc[r][c]);
    }
  }
}

extern "C" void kernel_launch(void* const* d_in, const int* in_sizes, int n_in,
                              void* d_out, int out_size, void* d_ws, size_t ws_size,
                              hipStream_t stream) {
  (void)in_sizes; (void)n_in; (void)out_size; (void)ws_size;
  const int* tokens = (const int*)d_in[0];
  const float* emb = (const float*)d_in[1];
  const float* W_ih = (const float*)d_in[2];
  const float* W_hh = (const float*)d_in[3];
  const float* b_ih = (const float*)d_in[4];
  const float* b_hh = (const float*)d_in[5];
  const float* w_fc = (const float*)d_in[6];
  const float* b_fc = (const float*)d_in[7];
  const float* Wq = (const float*)d_in[8];
  const float* bq = (const float*)d_in[9];
  const float* Wk = (const float*)d_in[10];
  const float* bk = (const float*)d_in[11];
  float* out = (float*)d_out;

  float* ws = (float*)d_ws;
  size_t o = 0;
  float* GI = ws + o;    o += (size_t)B * S * K3;
  float* GHCP = ws + o;  o += (size_t)B * S * K3;   // position-keyed W_hh@h1 cache
  float* H1P = ws + o;   o += (size_t)B * S * E;    // position-keyed h1 cache
  float* PAIR = ws + o;  o += (size_t)B * S * E;
  float* Wbig = ws + o;  o += (size_t)K3 * K3;      // [EW(1000) | 0(24) | W_ih^T(512)] k-major
  float* Gbig = ws + o;  o += (size_t)1512 * E;     // [G2(1000) ; Mqk(512)]
  float* H1V = ws + o;   o += (size_t)1024 * E;     // vocab h1 table
  float* GHCV = ws + o;  o += (size_t)1024 * K3;    // vocab W_hh@h1 table (+bhh)
  float* SCT = ws + o;   o += (size_t)B * K3;
  float* A2 = ws + o;    o += (size_t)B * K3;
  float* gb = ws + o;    o += 1024;
  float* v12 = ws + o;   o += 512;
  float* bw = ws + o;    o += 512;
  float* wv3 = ws + o;   o += 512;
  float* c0s = ws + o;   o += 16;
  float* SCR = ws + o;   o += B * 16;
  int* pos0 = (int*)(ws + o); o += B * 16;
  int* pos1 = (int*)(ws + o); o += B * 16;
  int* wlb = (int*)(ws + o);  o += NW0;
  int* wlL = (int*)(ws + o);  o += NW0;
  int* wlR = (int*)(ws + o);  o += NW0;
  int* xdst = (int*)(ws + o); o += B;

  // ---- setup: 5 launches ----
  k_prep<<<279, 256, 0, stream>>>(Wq, Wk, W_ih, Wbig, pos0, wlb, wlL, wlR, out,
                                  Gbig, bq, bk, v12, bw, wv3, c0s);
  k_gemmD<<<dim3(32, 16), 256, 0, stream>>>(emb, E, R, W_ih, K3, nullptr, Wbig, K3,
                                            Gbig + (size_t)1000 * E, 512, Gbig, E, E);
  k_setupB<<<1000 + B * S + 8 + 4, 256, 0, stream>>>(tokens, Wbig, b_ih, b_hh, emb,
                                                     wv3, GI, H1V, SCT, gb);
  k_gemm<<<dim3(24, 16), 256, 0, stream>>>(H1V, E, 1000, W_hh, K3, E, b_hh, 1.f,
                                           GHCV, K3);
  k_pairc0<<<NW0, 256, 0, stream>>>(tokens, GI, GHCV, H1V, w_fc, b_fc, PAIR, SCR,
                                    H1P, GHCP);

  // ---- 14 merge steps, 6 kernels each; only position xdst's h1/GHC recomputed ----
  for (int t = 0; t < 14; ++t) {
    int* pin = (t & 1) ? pos1 : pos0;
    int* pout = (t & 1) ? pos0 : pos1;
    k_qscsel<<<dim3(24, 4, 2), 256, 0, stream>>>(PAIR, SCR, pin, pout, wlb, wlL, wlR,
                                                 xdst, Gbig, SCT, GI, b_ih, GHCP, b_hh,
                                                 15 - t, 0);
    k_sm<<<B, 256, 0, stream>>>(SCT, PAIR, xdst, v12, bw, c0s, out, A2, gb, t, 0);
    k_giup<<<dim3(24, 4, 4), 256, 0, stream>>>(A2, Wbig, GI, xdst);
    k_h1c<<<B, 256, 0, stream>>>(xdst, GI, b_hh, H1P);
    k_ghcs<<<dim3(24, 4, 2), 256, 0, stream>>>(xdst, H1P, W_hh, GHCP);
    k_pairc<<<NWS, 256, 0, stream>>>(wlb, wlL, wlR, GI, GHCP, H1P, w_fc, b_fc, PAIR, SCR);
  }

  // ---- final: h2 = PAIR[b][pos0[b*16]]; attention, scores+loss straight to out ----
  k_qscsel<<<dim3(24, 4, 2), 256, 0, stream>>>(PAIR, SCR, pos0, pos1, wlb, wlL, wlR,
                                               xdst, Gbig, SCT, GI, b_ih, GHCP, b_hh,
                                               1, 1);
  k_sm<<<B, 256, 0, stream>>>(SCT, PAIR, xdst, v12, bw, c0s, out, A2, gb, 15, 1);
}

// Round 18
// 1304.631 us; speedup vs baseline: 1.0684x; 1.0150x over previous
//
#include <hip/hip_runtime.h>

#define B 128
#define S 16
#define E 512
#define R 1000
#define K3 1536
#define NW0 1920   // init worklist: 128 b * 15 pairs
#define NWS 256    // per-step worklist: 128 b * 2 entries
#define NS (B * (R + 1))
#define SCALE 0.04419417382415922f

static __device__ __forceinline__ float sigm(float x) { return 1.f / (1.f + expf(-x)); }

// ---------- block reductions (256 threads, tree — setup only) ----------
static __device__ __forceinline__ float brsum(float v, float* sb) {
  int tid = threadIdx.x;
  sb[tid] = v; __syncthreads();
  for (int s = 128; s > 0; s >>= 1) {
    if (tid < s) sb[tid] += sb[tid + s];
    __syncthreads();
  }
  float r = sb[0]; __syncthreads();
  return r;
}

// ---------- wave-butterfly reductions (256 threads = 4 waves of 64) ----------
static __device__ __forceinline__ float wrsum(float v, float* sb) {
  for (int off = 32; off > 0; off >>= 1) v += __shfl_xor(v, off);
  int tid = threadIdx.x, w = tid >> 6;
  if ((tid & 63) == 0) sb[w] = v;
  __syncthreads();
  float r = (sb[0] + sb[1]) + (sb[2] + sb[3]);
  __syncthreads();
  return r;
}
static __device__ __forceinline__ float wrmax(float v, float* sb) {
  for (int off = 32; off > 0; off >>= 1) v = fmaxf(v, __shfl_xor(v, off));
  int tid = threadIdx.x, w = tid >> 6;
  if ((tid & 63) == 0) sb[w] = v;
  __syncthreads();
  float r = fmaxf(fmaxf(sb[0], sb[1]), fmaxf(sb[2], sb[3]));
  __syncthreads();
  return r;
}
static __device__ __forceinline__ void wrsum2(float v1, float v2, float* sb, float* sb2,
                                              float* o1, float* o2) {
  for (int off = 32; off > 0; off >>= 1) {
    v1 += __shfl_xor(v1, off);
    v2 += __shfl_xor(v2, off);
  }
  int tid = threadIdx.x, w = tid >> 6;
  if ((tid & 63) == 0) { sb[w] = v1; sb2[w] = v2; }
  __syncthreads();
  *o1 = (sb[0] + sb[1]) + (sb[2] + sb[3]);
  *o2 = (sb2[0] + sb2[1]) + (sb2[2] + sb2[3]);
  __syncthreads();
}

#define TILE_FMA \
  _Pragma("unroll") \
  for (int k = 0; k < 16; ++k) { \
    float4 a4 = *(const float4*)&As[k][ty * 4]; \
    float4 w4 = *(const float4*)&Ws[k][tx * 4]; \
    acc[0][0] = fmaf(a4.x, w4.x, acc[0][0]); acc[0][1] = fmaf(a4.x, w4.y, acc[0][1]); \
    acc[0][2] = fmaf(a4.x, w4.z, acc[0][2]); acc[0][3] = fmaf(a4.x, w4.w, acc[0][3]); \
    acc[1][0] = fmaf(a4.y, w4.x, acc[1][0]); acc[1][1] = fmaf(a4.y, w4.y, acc[1][1]); \
    acc[1][2] = fmaf(a4.y, w4.z, acc[1][2]); acc[1][3] = fmaf(a4.y, w4.w, acc[1][3]); \
    acc[2][0] = fmaf(a4.z, w4.x, acc[2][0]); acc[2][1] = fmaf(a4.z, w4.y, acc[2][1]); \
    acc[2][2] = fmaf(a4.z, w4.z, acc[2][2]); acc[2][3] = fmaf(a4.z, w4.w, acc[2][3]); \
    acc[3][0] = fmaf(a4.w, w4.x, acc[3][0]); acc[3][1] = fmaf(a4.w, w4.y, acc[3][1]); \
    acc[3][2] = fmaf(a4.w, w4.z, acc[3][2]); acc[3][3] = fmaf(a4.w, w4.w, acc[3][3]); \
  }

// 32-row-tile inner product: acc[2][4], A in As[16][32], W in Ws[16][64]
#define TILE_FMA32 \
  _Pragma("unroll") \
  for (int k = 0; k < 16; ++k) { \
    float2 a2 = *(const float2*)&As[k][ty * 2]; \
    float4 w4 = *(const float4*)&Ws[k][tx * 4]; \
    acc[0][0] = fmaf(a2.x, w4.x, acc[0][0]); acc[0][1] = fmaf(a2.x, w4.y, acc[0][1]); \
    acc[0][2] = fmaf(a2.x, w4.z, acc[0][2]); acc[0][3] = fmaf(a2.x, w4.w, acc[0][3]); \
    acc[1][0] = fmaf(a2.y, w4.x, acc[1][0]); acc[1][1] = fmaf(a2.y, w4.y, acc[1][1]); \
    acc[1][2] = fmaf(a2.y, w4.z, acc[1][2]); acc[1][3] = fmaf(a2.y, w4.w, acc[1][3]); \
  }

// ---------- generic tiled gemm (standalone body — VGPR~44 codegen) ----------
__global__ __launch_bounds__(256) void k_gemm(const float* __restrict__ A, int lda, int M,
                                              const float* __restrict__ W, int N, int K,
                                              const float* __restrict__ bias, float scale,
                                              float* __restrict__ C, int ldc) {
  __shared__ float As[16][64];
  __shared__ float Ws[16][64];
  int tid = threadIdx.x;
  int mBase = blockIdx.y * 64;
  int nBase = blockIdx.x * 64;
  int tx = tid & 15, ty = tid >> 4;
  int li = tid & 63;
  int lk = (tid >> 6) * 4;
  float acc[4][4] = {{0.f,0.f,0.f,0.f},{0.f,0.f,0.f,0.f},{0.f,0.f,0.f,0.f},{0.f,0.f,0.f,0.f}};
  int m = mBase + li;
  const float* Arow = (m < M) ? (A + (size_t)m * lda) : nullptr;
  int n = nBase + li;
  const float* Wrow = (n < N) ? (W + (size_t)n * K) : nullptr;

  float4 av = Arow ? *(const float4*)(Arow + lk) : make_float4(0.f, 0.f, 0.f, 0.f);
  float4 wv = Wrow ? *(const float4*)(Wrow + lk) : make_float4(0.f, 0.f, 0.f, 0.f);

  for (int k0 = 0; k0 < K; k0 += 16) {
    As[lk + 0][li] = av.x; As[lk + 1][li] = av.y;
    As[lk + 2][li] = av.z; As[lk + 3][li] = av.w;
    Ws[lk + 0][li] = wv.x; Ws[lk + 1][li] = wv.y;
    Ws[lk + 2][li] = wv.z; Ws[lk + 3][li] = wv.w;
    __syncthreads();
    if (k0 + 16 < K) {
      av = Arow ? *(const float4*)(Arow + k0 + 16 + lk) : make_float4(0.f, 0.f, 0.f, 0.f);
      wv = Wrow ? *(const float4*)(Wrow + k0 + 16 + lk) : make_float4(0.f, 0.f, 0.f, 0.f);
    }
    TILE_FMA
    __syncthreads();
  }
#pragma unroll
  for (int r = 0; r < 4; ++r) {
    int mm = mBase + ty * 4 + r;
    if (mm >= M) continue;
#pragma unroll
    for (int c = 0; c < 4; ++c) {
      int nn = nBase + tx * 4 + c;
      if (nn >= N) continue;
      float v = acc[r][c] * scale;
      if (bias) v += bias[nn];
      C[(size_t)mm * ldc + nn] = v;
    }
  }
}

// ---------- dual-output gemm: n<N1 -> W1,C1 ; else W2,C2 ----------
__global__ __launch_bounds__(256) void k_gemmD(const float* __restrict__ A, int lda, int M,
                                               const float* __restrict__ W1, int N1,
                                               const float* __restrict__ b1,
                                               float* __restrict__ C1, int ldc1,
                                               const float* __restrict__ W2, int N2,
                                               float* __restrict__ C2, int ldc2, int K) {
  __shared__ float As[16][64];
  __shared__ float Ws[16][64];
  int tid = threadIdx.x;
  int mBase = blockIdx.y * 64;
  int nBase = blockIdx.x * 64;
  int tx = tid & 15, ty = tid >> 4;
  int li = tid & 63;
  int lk = (tid >> 6) * 4;
  float acc[4][4] = {{0.f,0.f,0.f,0.f},{0.f,0.f,0.f,0.f},{0.f,0.f,0.f,0.f},{0.f,0.f,0.f,0.f}};
  int m = mBase + li;
  const float* Arow = (m < M) ? (A + (size_t)m * lda) : nullptr;
  int n = nBase + li;
  const float* Wrow = nullptr;
  if (n < N1) Wrow = W1 + (size_t)n * K;
  else if (n < N1 + N2) Wrow = W2 + (size_t)(n - N1) * K;

  float4 av = Arow ? *(const float4*)(Arow + lk) : make_float4(0.f, 0.f, 0.f, 0.f);
  float4 wv = Wrow ? *(const float4*)(Wrow + lk) : make_float4(0.f, 0.f, 0.f, 0.f);

  for (int k0 = 0; k0 < K; k0 += 16) {
    As[lk + 0][li] = av.x; As[lk + 1][li] = av.y;
    As[lk + 2][li] = av.z; As[lk + 3][li] = av.w;
    Ws[lk + 0][li] = wv.x; Ws[lk + 1][li] = wv.y;
    Ws[lk + 2][li] = wv.z; Ws[lk + 3][li] = wv.w;
    __syncthreads();
    if (k0 + 16 < K) {
      av = Arow ? *(const float4*)(Arow + k0 + 16 + lk) : make_float4(0.f, 0.f, 0.f, 0.f);
      wv = Wrow ? *(const float4*)(Wrow + k0 + 16 + lk) : make_float4(0.f, 0.f, 0.f, 0.f);
    }
    TILE_FMA
    __syncthreads();
  }
#pragma unroll
  for (int r = 0; r < 4; ++r) {
    int mm = mBase + ty * 4 + r;
    if (mm >= M) continue;
#pragma unroll
    for (int c = 0; c < 4; ++c) {
      int nn = nBase + tx * 4 + c;
      if (nn < N1) {
        float v = acc[r][c];
        if (b1) v += b1[nn];
        C1[(size_t)mm * ldc1 + nn] = v;
      } else if (nn < N1 + N2) {
        C2[(size_t)mm * ldc2 + (nn - N1)] = acc[r][c];
      }
    }
  }
}

// ---------- 64x64 transpose tile (device) ----------
static __device__ void dev_tr64(float (*t)[65], int tid, const float* __restrict__ src,
                                int Cc, float* __restrict__ dst, int ldd, int bx, int by) {
  int tx = tid & 15, ty = tid >> 4;
  int rb = by * 64, cb = bx * 64;
#pragma unroll
  for (int i = 0; i < 4; ++i) {
    int r = rb + ty + i * 16;
    float4 v = *(const float4*)(src + (size_t)r * Cc + cb + tx * 4);
    t[ty + i * 16][tx * 4 + 0] = v.x; t[ty + i * 16][tx * 4 + 1] = v.y;
    t[ty + i * 16][tx * 4 + 2] = v.z; t[ty + i * 16][tx * 4 + 3] = v.w;
  }
  __syncthreads();
#pragma unroll
  for (int i = 0; i < 4; ++i) {
    int c = cb + ty + i * 16;
    float4 v;
    v.x = t[tx * 4 + 0][ty + i * 16]; v.y = t[tx * 4 + 1][ty + i * 16];
    v.z = t[tx * 4 + 2][ty + i * 16]; v.w = t[tx * 4 + 3][ty + i * 16];
    *(float4*)(dst + (size_t)c * ldd + rb + tx * 4) = v;
  }
}

// ---------- setup L1: Wih transpose + initwl + pad + out14 + Mqk NT-gemm + v12/bw/wv3/c0 ----
__global__ __launch_bounds__(256) void k_prep(const float* __restrict__ Wq,
                                              const float* __restrict__ Wk,
                                              const float* __restrict__ Wih,
                                              float* __restrict__ Wbig,
                                              int* __restrict__ pos,
                                              int* __restrict__ wlb,
                                              int* __restrict__ wlL,
                                              int* __restrict__ wlR,
                                              float* __restrict__ outp,
                                              float* __restrict__ Gbig,
                                              const float* __restrict__ bq,
                                              const float* __restrict__ bk,
                                              float* __restrict__ v12,
                                              float* __restrict__ bw,
                                              float* __restrict__ wv3,
                                              float* __restrict__ c0s) {
  __shared__ float t[64][65];
  int blk = blockIdx.x, tid = threadIdx.x;
  if (blk < 192) {
    dev_tr64(t, tid, Wih, E, Wbig + (size_t)1024 * K3, K3, blk & 7, blk >> 3);
  } else if (blk < 200) {
    int idx = (blk - 192) * 256 + tid;
    if (idx < B * 16) pos[idx] = idx & 15;
    if (idx < NW0) {
      wlb[idx] = idx / 15;
      int i = idx % 15;
      wlL[idx] = i;
      wlR[idx] = i + 1;
    }
    if (idx < B) outp[NS + idx * 16 + 14] = 0.f;  // loss col 14 is identically 0
  } else if (blk < 208) {
    int idx = (blk - 200) * 256 + tid;
    for (int i = idx; i < 24 * K3; i += 8 * 256) Wbig[(size_t)1000 * K3 + i] = 0.f;
  } else if (blk < 272) {
    // Mqk[i,f] = sum_e Wq[e,i]*Wk[e,f]  (NT gemm, no transposes needed)
    int j = blk - 208;
    int fT = (j & 7) * 64, iT = (j >> 3) * 64;
    float (*As)[64] = (float(*)[64])&t[0][0];
    float (*Ws)[64] = (float(*)[64])&t[20][0];
    int tx = tid & 15, ty = tid >> 4;
    int li = tid & 63, lk = (tid >> 6) * 4;
    float acc[4][4] = {{0.f,0.f,0.f,0.f},{0.f,0.f,0.f,0.f},{0.f,0.f,0.f,0.f},{0.f,0.f,0.f,0.f}};
    float a0 = Wq[(size_t)(lk + 0) * E + iT + li];
    float a1 = Wq[(size_t)(lk + 1) * E + iT + li];
    float a2 = Wq[(size_t)(lk + 2) * E + iT + li];
    float a3 = Wq[(size_t)(lk + 3) * E + iT + li];
    float w0 = Wk[(size_t)(lk + 0) * E + fT + li];
    float w1 = Wk[(size_t)(lk + 1) * E + fT + li];
    float w2 = Wk[(size_t)(lk + 2) * E + fT + li];
    float w3 = Wk[(size_t)(lk + 3) * E + fT + li];
    for (int e0 = 0; e0 < E; e0 += 16) {
      As[lk + 0][li] = a0; As[lk + 1][li] = a1;
      As[lk + 2][li] = a2; As[lk + 3][li] = a3;
      Ws[lk + 0][li] = w0; Ws[lk + 1][li] = w1;
      Ws[lk + 2][li] = w2; Ws[lk + 3][li] = w3;
      __syncthreads();
      if (e0 + 16 < E) {
        a0 = Wq[(size_t)(e0 + 16 + lk + 0) * E + iT + li];
        a1 = Wq[(size_t)(e0 + 16 + lk + 1) * E + iT + li];
        a2 = Wq[(size_t)(e0 + 16 + lk + 2) * E + iT + li];
        a3 = Wq[(size_t)(e0 + 16 + lk + 3) * E + iT + li];
        w0 = Wk[(size_t)(e0 + 16 + lk + 0) * E + fT + li];
        w1 = Wk[(size_t)(e0 + 16 + lk + 1) * E + fT + li];
        w2 = Wk[(size_t)(e0 + 16 + lk + 2) * E + fT + li];
        w3 = Wk[(size_t)(e0 + 16 + lk + 3) * E + fT + li];
      }
      TILE_FMA
      __syncthreads();
    }
#pragma unroll
    for (int r = 0; r < 4; ++r)
#pragma unroll
      for (int c = 0; c < 4; ++c)
        Gbig[(size_t)(1000 + iT + ty * 4 + r) * E + fT + tx * 4 + c] = acc[r][c];
  } else if (blk < 274) {
    int i = (blk - 272) * 256 + tid;
    float s = 0.f;
    for (int e = 0; e < E; ++e) s += Wq[(size_t)e * E + i] * bk[e] + bq[e] * Wk[(size_t)e * E + i];
    v12[i] = s;
  } else if (blk < 276) {
    int i = (blk - 274) * 256 + tid;
    float s = 0.f;
    for (int e = 0; e < E; ++e) s += bk[e] * Wq[(size_t)e * E + i];
    bw[i] = s;
  } else if (blk < 278) {
    int f = (blk - 276) * 256 + tid;
    float s = 0.f;
    for (int e = 0; e < E; ++e) s += bq[e] * Wk[(size_t)e * E + f];
    wv3[f] = s;
  } else {
    float* sb = &t[0][0];
    float p = 0.f;
    for (int e = tid; e < E; e += 256) p += bq[e] * bk[e];
    float s = brsum(p, sb);
    if (tid == 0) c0s[0] = s;
  }
}

// ---------- setup B: H1V vocab h1 [0,1000) | GI gather [1000,3048) | SCT zero | gb ----------
__global__ __launch_bounds__(256) void k_setupB(const int* __restrict__ tokens,
                                                const float* __restrict__ Wbig,
                                                const float* __restrict__ bih,
                                                const float* __restrict__ bhh,
                                                const float* __restrict__ emb,
                                                const float* __restrict__ wv3,
                                                float* __restrict__ GI,
                                                float* __restrict__ H1V,
                                                float* __restrict__ SCT,
                                                float* __restrict__ gb) {
  int blk = blockIdx.x, tid = threadIdx.x;
  if (blk < 1000) {
    const float* ew = Wbig + (size_t)blk * K3;
    float* h = H1V + (size_t)blk * E;
    for (int e = tid; e < E; e += 256) {
      float g0 = ew[e] + bih[e];
      float g1 = ew[E + e] + bih[E + e];
      float g2 = ew[2 * E + e] + bih[2 * E + e];
      float r = sigm(g0 + bhh[e]);
      float z = sigm(g1 + bhh[E + e]);
      h[e] = (1.f - z) * tanhf(g2 + r * bhh[2 * E + e]);
    }
  } else if (blk < 1000 + B * S) {
    int p = blk - 1000;
    int tok = tokens[p];
    const float4* src = (const float4*)(Wbig + (size_t)tok * K3);
    const float4* bv = (const float4*)bih;
    float4* dst = (float4*)(GI + (size_t)p * K3);
    for (int i = tid; i < K3 / 4; i += 256) {
      float4 a = src[i], b = bv[i];
      dst[i] = make_float4(a.x + b.x, a.y + b.y, a.z + b.z, a.w + b.w);
    }
  } else if (blk < 1000 + B * S + 8) {
    int rb = blk - (1000 + B * S);
    for (int m = rb * 16; m < rb * 16 + 16; ++m) {
      float* r = SCT + (size_t)m * K3;
      for (int n = tid; n < 1512; n += 256) r[n] = 0.f;
    }
  } else {
    int r = (blk - (1000 + B * S + 8)) * 256 + tid;
    if (r < R) {
      const float* er = emb + (size_t)r * E;
      float s = 0.f;
      for (int f = 0; f < E; ++f) s += er[f] * wv3[f];
      gb[r] = s;  // raw: score adds (gb + SP.bw + c0)
    }
  }
}

// ---------- setup pairc: compute PAIR/SCR from vocab tables + gather position caches ----
__global__ __launch_bounds__(256) void k_pairc0(const int* __restrict__ tokens,
                                                const float* __restrict__ GI,
                                                const float* __restrict__ GHCV,
                                                const float* __restrict__ H1V,
                                                const float* __restrict__ wfc,
                                                const float* __restrict__ bfc,
                                                float* __restrict__ PAIR,
                                                float* __restrict__ SCR,
                                                float* __restrict__ H1P,
                                                float* __restrict__ GHCP) {
  __shared__ float sb[4];
  int w = blockIdx.x, tid = threadIdx.x;
  int b = w / 15, i = w % 15;
  int lp = b * 16 + i;
  int tok = tokens[lp];
  const float* gr = GI + (size_t)(lp + 1) * K3;
  const float* gh = GHCV + (size_t)tok * K3;
  const float* h = H1V + (size_t)tok * E;
  float* ghp = GHCP + (size_t)lp * K3;
  float* hp = H1P + (size_t)lp * E;
  float* p = PAIR + (size_t)lp * E;
  float part = 0.f;
  for (int e = tid; e < E; e += 256) {
    float g0 = gh[e], g1 = gh[E + e], g2 = gh[2 * E + e], he = h[e];
    ghp[e] = g0; ghp[E + e] = g1; ghp[2 * E + e] = g2; hp[e] = he;
    float r = sigm(gr[e] + g0);
    float z = sigm(gr[E + e] + g1);
    float n = tanhf(gr[2 * E + e] + r * g2);
    float pv = (1.f - z) * n + z * he;
    p[e] = pv;
    part += pv * wfc[e];
  }
  float d = wrsum(part, sb);
  if (tid == 0) SCR[lp] = sigm(d + bfc[0]);
}

// ---------- per-step h1: one block per batch; recompute position xdst[b] ----------
__global__ __launch_bounds__(256) void k_h1c(const int* __restrict__ xdst,
                                             const float* __restrict__ GI,
                                             const float* __restrict__ bhh,
                                             float* __restrict__ H1P) {
  int p = xdst[blockIdx.x], tid = threadIdx.x;
  const float* gi = GI + (size_t)p * K3;
  float* h = H1P + (size_t)p * E;
  for (int e = tid; e < E; e += 256) {
    float r = sigm(gi[e] + bhh[e]);
    float z = sigm(gi[E + e] + bhh[E + e]);
    h[e] = (1.f - z) * tanhf(gi[2 * E + e] + r * bhh[2 * E + e]);
  }
}

// ---------- GHC split-K gemm, 32-row tiles, position-indirect: grid (24, 4, 2) ----------
__global__ __launch_bounds__(256) void k_ghcs(const int* __restrict__ xdst,
                                              const float* __restrict__ H1P,
                                              const float* __restrict__ Whh,
                                              float* __restrict__ GHCP) {
  __shared__ float As[16][32];
  __shared__ float Ws[16][64];
  __shared__ int sp[32];
  int tid = threadIdx.x;
  int nBase = blockIdx.x * 64;
  int mBase = blockIdx.y * 32;
  int kbeg = blockIdx.z * 256;
  if (tid < 32) sp[tid] = xdst[mBase + tid];
  __syncthreads();
  int tx = tid & 15, ty = tid >> 4;
  int ar = tid & 31, ak = (tid >> 5) * 2;
  int li = tid & 63, lk = (tid >> 6) * 4;
  float acc[2][4] = {{0.f,0.f,0.f,0.f},{0.f,0.f,0.f,0.f}};
  const float* Arow = H1P + (size_t)sp[ar] * E + kbeg;
  const float* Wrow = Whh + (size_t)(nBase + li) * E + kbeg;
  float2 av = *(const float2*)(Arow + ak);
  float4 wv = *(const float4*)(Wrow + lk);
  for (int k0 = 0; k0 < 256; k0 += 16) {
    As[ak + 0][ar] = av.x; As[ak + 1][ar] = av.y;
    Ws[lk + 0][li] = wv.x; Ws[lk + 1][li] = wv.y;
    Ws[lk + 2][li] = wv.z; Ws[lk + 3][li] = wv.w;
    __syncthreads();
    if (k0 + 16 < 256) {
      av = *(const float2*)(Arow + k0 + 16 + ak);
      wv = *(const float4*)(Wrow + k0 + 16 + lk);
    }
    TILE_FMA32
    __syncthreads();
  }
#pragma unroll
  for (int r = 0; r < 2; ++r) {
    size_t crow = (size_t)sp[ty * 2 + r] * K3;
#pragma unroll
    for (int c = 0; c < 4; ++c) {
      int nn = nBase + tx * 4 + c;
      atomicAdd(&GHCP[crow + nn], acc[r][c]);
    }
  }
}

// ---------- pair + fc score (position-keyed H1P/GHCP caches) ----------
__global__ __launch_bounds__(256) void k_pairc(const int* __restrict__ wlb,
                                               const int* __restrict__ wlL,
                                               const int* __restrict__ wlR,
                                               const float* __restrict__ GI,
                                               const float* __restrict__ GHCP,
                                               const float* __restrict__ H1P,
                                               const float* __restrict__ wfc,
                                               const float* __restrict__ bfc,
                                               float* __restrict__ PAIR,
                                               float* __restrict__ SCR) {
  __shared__ float sb[4];
  int w = blockIdx.x, tid = threadIdx.x;
  int b = wlb[w], ls = wlL[w], rs = wlR[w];
  int lp = b * 16 + ls;
  const float* gr = GI + (size_t)(b * 16 + rs) * K3;
  const float* gh = GHCP + (size_t)lp * K3;
  const float* h = H1P + (size_t)lp * E;
  float* p = PAIR + (size_t)lp * E;
  float part = 0.f;
  for (int e = tid; e < E; e += 256) {
    float r = sigm(gr[e] + gh[e]);
    float z = sigm(gr[E + e] + gh[E + e]);
    float n = tanhf(gr[2 * E + e] + r * gh[2 * E + e]);
    float pv = (1.f - z) * n + z * h[e];
    p[e] = pv;
    part += pv * wfc[e];
  }
  float d = wrsum(part, sb);
  if (tid == 0) SCR[b * 16 + ls] = sigm(d + bfc[0]);
}

// ---------- fused sel + scores split-K gemm, 32-row tiles: grid (24, 4, 2) ----------
// Block (0, y, 0) writes pos/wl/xdst; z==1: x<16 write GI[xdst]=bih (2 rows each),
// x in [16,24) write GHCP[xdst]=bhh (4 rows each). float4 stores.
__global__ __launch_bounds__(256) void k_qscsel(const float* __restrict__ PAIR,
                                                const float* __restrict__ SCR,
                                                const int* __restrict__ pin,
                                                int* __restrict__ pout,
                                                int* __restrict__ wlb,
                                                int* __restrict__ wlL,
                                                int* __restrict__ wlR,
                                                int* __restrict__ xdst,
                                                const float* __restrict__ Gbig,
                                                float* __restrict__ SCT,
                                                float* __restrict__ GI,
                                                const float* __restrict__ bih,
                                                float* __restrict__ GHCP,
                                                const float* __restrict__ bhh,
                                                int P, int finalMode) {
  __shared__ float As[16][32];
  __shared__ float Ws[16][64];
  __shared__ int sxd[32];
  int tid = threadIdx.x;
  int nBase = blockIdx.x * 64;
  int mBase = blockIdx.y * 32;
  int kbeg = blockIdx.z * 256;
  if (tid < 32) {
    int b = mBase + tid;
    if (finalMode) {
      int xr = b * 16 + pin[b * 16];
      sxd[tid] = xr;
      if (blockIdx.x == 0 && blockIdx.z == 0) xdst[b] = xr;
    } else {
      int L = P + 1;
      int lp[16];
      for (int i = 0; i < L; ++i) lp[i] = pin[b * 16 + i];
      float best = -1e30f; int sel = 0;
      for (int i = 0; i < P; ++i) {
        float v = SCR[b * 16 + lp[i]];
        if (v > best) { best = v; sel = i; }
      }
      int r1i = (sel + 2 < L) ? sel + 2 : L - 1;
      int l1 = lp[sel], r1 = lp[r1i];
      int l0 = (sel > 0) ? lp[sel - 1] : l1;
      int r0 = (sel > 0) ? lp[sel] : r1;
      sxd[tid] = b * 16 + l1;
      if (blockIdx.x == 0 && blockIdx.z == 0) {
        wlb[2 * b] = b;     wlL[2 * b] = l0;     wlR[2 * b] = r0;
        wlb[2 * b + 1] = b; wlL[2 * b + 1] = l1; wlR[2 * b + 1] = r1;
        xdst[b] = b * 16 + l1;
        for (int i = 0; i < L - 1; ++i)
          pout[b * 16 + i] = (i <= sel) ? lp[i] : lp[i + 1];
      }
    }
  }
  __syncthreads();
  // Early cache-row inits, off the k_sm/k_h1c critical paths (duplicate-safe writes):
  // old GI[xdst]/GHCP[xdst] values have no readers after this point this step.
  if (!finalMode && blockIdx.z == 1) {
    if (blockIdx.x < 16) {
#pragma unroll
      for (int r = 0; r < 2; ++r) {
        float4* g = (float4*)(GI + (size_t)sxd[blockIdx.x * 2 + r] * K3);
        const float4* s = (const float4*)bih;
        for (int i = tid; i < K3 / 4; i += 256) g[i] = s[i];
      }
    } else {
#pragma unroll
      for (int r = 0; r < 4; ++r) {
        float4* g = (float4*)(GHCP + (size_t)sxd[(blockIdx.x - 16) * 4 + r] * K3);
        const float4* s = (const float4*)bhh;
        for (int i = tid; i < K3 / 4; i += 256) g[i] = s[i];
      }
    }
  }
  int tx = tid & 15, ty = tid >> 4;
  int ar = tid & 31, ak = (tid >> 5) * 2;
  int li = tid & 63, lk = (tid >> 6) * 4;
  float acc[2][4] = {{0.f,0.f,0.f,0.f},{0.f,0.f,0.f,0.f}};
  const float* Arow = PAIR + (size_t)sxd[ar] * E + kbeg;
  int n = nBase + li;
  const float* Wrow = (n < 1512) ? (Gbig + (size_t)n * E + kbeg) : nullptr;
  float2 av = *(const float2*)(Arow + ak);
  float4 wv = Wrow ? *(const float4*)(Wrow + lk) : make_float4(0.f, 0.f, 0.f, 0.f);
  for (int k0 = 0; k0 < 256; k0 += 16) {
    As[ak + 0][ar] = av.x; As[ak + 1][ar] = av.y;
    Ws[lk + 0][li] = wv.x; Ws[lk + 1][li] = wv.y;
    Ws[lk + 2][li] = wv.z; Ws[lk + 3][li] = wv.w;
    __syncthreads();
    if (k0 + 16 < 256) {
      av = *(const float2*)(Arow + k0 + 16 + ak);
      wv = Wrow ? *(const float4*)(Wrow + k0 + 16 + lk) : make_float4(0.f, 0.f, 0.f, 0.f);
    }
    TILE_FMA32
    __syncthreads();
  }
#pragma unroll
  for (int r = 0; r < 2; ++r) {
    int mm = mBase + ty * 2 + r;
#pragma unroll
    for (int c = 0; c < 4; ++c) {
      int nn = nBase + tx * 4 + c;
      if (nn < 1512) atomicAdd(&SCT[(size_t)mm * K3 + nn], acc[r][c]);
    }
  }
}

// ---------- softmax/entropy + A2 build + SCT re-init (zeros, float4) ----------
// SCT holds RAW dots; score = (SCT + gb_raw + SP.bw + c0)*SCALE.
__global__ __launch_bounds__(256) void k_sm(float* __restrict__ SCT,
                                            const float* __restrict__ PAIR,
                                            const int* __restrict__ xdst,
                                            const float* __restrict__ v12,
                                            const float* __restrict__ bw,
                                            const float* __restrict__ c0s,
                                            float* __restrict__ outp,
                                            float* __restrict__ A2,
                                            const float* __restrict__ gb,
                                            int t, int finalMode) {
  __shared__ float sb[4];
  __shared__ float sb2[4];
  __shared__ float sps[E];
  int b = blockIdx.x, tid = threadIdx.x;
  float* row = SCT + (size_t)b * K3;
  int xr = xdst[b];
  const float* sp = PAIR + (size_t)xr * E;
  for (int i = tid; i < E; i += 256) sps[i] = sp[i];
  __syncthreads();
  // bilinear self-score (Mqk part in cols 1000..1511) + SP.bw shift, one paired reduce
  float part = 0.f, pbw = 0.f;
  for (int i = tid; i < E; i += 256) {
    part += sps[i] * (row[1000 + i] + v12[i]);
    pbw += sps[i] * bw[i];
  }
  float ps, pb;
  wrsum2(part, pbw, sb, sb2, &ps, &pb);
  float last = (ps + c0s[0]) * SCALE;
  float shift = pb + c0s[0];
  float s[4];
  float ml = last;
#pragma unroll
  for (int q = 0; q < 4; ++q) {
    int j = tid + q * 256;
    s[q] = (j < 1000) ? (row[j] + gb[j] + shift) * SCALE : -1e30f;
    ml = fmaxf(ml, s[q]);
  }
  float mx = wrmax(ml, sb);
  float zp = 0.f, s1p = 0.f;
#pragma unroll
  for (int q = 0; q < 4; ++q) {
    int j = tid + q * 256;
    if (j < 1000) { float e = expf(s[q] - mx); zp += e; s1p += e * s[q]; }
  }
  if (tid == 0) { float e = expf(last - mx); zp += e; s1p += e * last; }
  float z, s1;
  wrsum2(zp, s1p, sb, sb2, &z, &s1);
  if (tid == 0) outp[NS + b * 16 + t] = mx + logf(z) - s1 / z;
  if (!finalMode) {
    float inv = 1.f / z;
    float* a = A2 + (size_t)b * K3;
#pragma unroll
    for (int q = 0; q < 4; ++q) {
      int j = tid + q * 256;
      if (j < 1000) a[j] = expf(s[q] - mx) * inv;
    }
    if (tid < 24) a[1000 + tid] = 0.f;
    float pr = expf(last - mx) * inv;
    for (int i = tid; i < E; i += 256) a[1024 + i] = pr * sps[i];
    // re-init SCT row to zeros for the next step's split-K accumulation (float4)
    float4* r4 = (float4*)row;
    for (int n2 = tid; n2 < 1512 / 4; n2 += 256) r4[n2] = make_float4(0.f, 0.f, 0.f, 0.f);
  } else {
    float* so = outp + (size_t)b * (R + 1);
#pragma unroll
    for (int q = 0; q < 4; ++q) {
      int j = tid + q * 256;
      if (j < 1000) so[j] = s[q];
    }
    if (tid == 0) so[R] = last;
  }
}

// ---------- fused merged+GI gemm, split-K atomic, 32-row tiles, reg-prefetch:
// grid (24,4,4) ----------
__global__ __launch_bounds__(256) void k_giup(const float* __restrict__ A2,
                                              const float* __restrict__ Wbig,
                                              float* __restrict__ GI,
                                              const int* __restrict__ xdst) {
  __shared__ float As[16][32];
  __shared__ float Ws[16][64];
  int tid = threadIdx.x;
  int nBase = blockIdx.x * 64;
  int mBase = blockIdx.y * 32;
  int kbeg = blockIdx.z * 384;
  int kend = kbeg + 384;
  int tx = tid & 15, ty = tid >> 4;
  int ar = tid & 31, ak = (tid >> 5) * 2;
  int li = tid & 63, wr = tid >> 6;
  float acc[2][4] = {{0.f,0.f,0.f,0.f},{0.f,0.f,0.f,0.f}};
  const float* Arow = A2 + (size_t)(mBase + ar) * K3;
  float2 av = *(const float2*)(Arow + kbeg + ak);
  float w0 = Wbig[(size_t)(kbeg + wr * 4 + 0) * K3 + nBase + li];
  float w1 = Wbig[(size_t)(kbeg + wr * 4 + 1) * K3 + nBase + li];
  float w2 = Wbig[(size_t)(kbeg + wr * 4 + 2) * K3 + nBase + li];
  float w3 = Wbig[(size_t)(kbeg + wr * 4 + 3) * K3 + nBase + li];
  for (int k0 = kbeg; k0 < kend; k0 += 16) {
    As[ak + 0][ar] = av.x; As[ak + 1][ar] = av.y;
    Ws[wr * 4 + 0][li] = w0; Ws[wr * 4 + 1][li] = w1;
    Ws[wr * 4 + 2][li] = w2; Ws[wr * 4 + 3][li] = w3;
    __syncthreads();
    if (k0 + 16 < kend) {  // register prefetch of next tile
      av = *(const float2*)(Arow + k0 + 16 + ak);
      w0 = Wbig[(size_t)(k0 + 16 + wr * 4 + 0) * K3 + nBase + li];
      w1 = Wbig[(size_t)(k0 + 16 + wr * 4 + 1) * K3 + nBase + li];
      w2 = Wbig[(size_t)(k0 + 16 + wr * 4 + 2) * K3 + nBase + li];
      w3 = Wbig[(size_t)(k0 + 16 + wr * 4 + 3) * K3 + nBase + li];
    }
    TILE_FMA32
    __syncthreads();
  }
#pragma unroll
  for (int r = 0; r < 2; ++r) {
    int mm = mBase + ty * 2 + r;
    size_t crow = (size_t)xdst[mm] * K3;
#pragma unroll
    for (int c = 0; c < 4; ++c) {
      int nn = nBase + tx * 4 + c;
      atomicAdd(&GI[crow + nn], acc[r][c]);
    }
  }
}

extern "C" void kernel_launch(void* const* d_in, const int* in_sizes, int n_in,
                              void* d_out, int out_size, void* d_ws, size_t ws_size,
                              hipStream_t stream) {
  (void)in_sizes; (void)n_in; (void)out_size; (void)ws_size;
  const int* tokens = (const int*)d_in[0];
  const float* emb = (const float*)d_in[1];
  const float* W_ih = (const float*)d_in[2];
  const float* W_hh = (const float*)d_in[3];
  const float* b_ih = (const float*)d_in[4];
  const float* b_hh = (const float*)d_in[5];
  const float* w_fc = (const float*)d_in[6];
  const float* b_fc = (const float*)d_in[7];
  const float* Wq = (const float*)d_in[8];
  const float* bq = (const float*)d_in[9];
  const float* Wk = (const float*)d_in[10];
  const float* bk = (const float*)d_in[11];
  float* out = (float*)d_out;

  float* ws = (float*)d_ws;
  size_t o = 0;
  float* GI = ws + o;    o += (size_t)B * S * K3;
  float* GHCP = ws + o;  o += (size_t)B * S * K3;   // position-keyed W_hh@h1 cache
  float* H1P = ws + o;   o += (size_t)B * S * E;    // position-keyed h1 cache
  float* PAIR = ws + o;  o += (size_t)B * S * E;
  float* Wbig = ws + o;  o += (size_t)K3 * K3;      // [EW(1000) | 0(24) | W_ih^T(512)] k-major
  float* Gbig = ws + o;  o += (size_t)1512 * E;     // [G2(1000) ; Mqk(512)]
  float* H1V = ws + o;   o += (size_t)1024 * E;     // vocab h1 table
  float* GHCV = ws + o;  o += (size_t)1024 * K3;    // vocab W_hh@h1 table (+bhh)
  float* SCT = ws + o;   o += (size_t)B * K3;
  float* A2 = ws + o;    o += (size_t)B * K3;
  float* gb = ws + o;    o += 1024;
  float* v12 = ws + o;   o += 512;
  float* bw = ws + o;    o += 512;
  float* wv3 = ws + o;   o += 512;
  float* c0s = ws + o;   o += 16;
  float* SCR = ws + o;   o += B * 16;
  int* pos0 = (int*)(ws + o); o += B * 16;
  int* pos1 = (int*)(ws + o); o += B * 16;
  int* wlb = (int*)(ws + o);  o += NW0;
  int* wlL = (int*)(ws + o);  o += NW0;
  int* wlR = (int*)(ws + o);  o += NW0;
  int* xdst = (int*)(ws + o); o += B;

  // ---- setup: 5 launches ----
  k_prep<<<279, 256, 0, stream>>>(Wq, Wk, W_ih, Wbig, pos0, wlb, wlL, wlR, out,
                                  Gbig, bq, bk, v12, bw, wv3, c0s);
  k_gemmD<<<dim3(32, 16), 256, 0, stream>>>(emb, E, R, W_ih, K3, nullptr, Wbig, K3,
                                            Gbig + (size_t)1000 * E, 512, Gbig, E, E);
  k_setupB<<<1000 + B * S + 8 + 4, 256, 0, stream>>>(tokens, Wbig, b_ih, b_hh, emb,
                                                     wv3, GI, H1V, SCT, gb);
  k_gemm<<<dim3(24, 16), 256, 0, stream>>>(H1V, E, 1000, W_hh, K3, E, b_hh, 1.f,
                                           GHCV, K3);
  k_pairc0<<<NW0, 256, 0, stream>>>(tokens, GI, GHCV, H1V, w_fc, b_fc, PAIR, SCR,
                                    H1P, GHCP);

  // ---- 14 merge steps, 6 kernels each; only position xdst's h1/GHC recomputed ----
  for (int t = 0; t < 14; ++t) {
    int* pin = (t & 1) ? pos1 : pos0;
    int* pout = (t & 1) ? pos0 : pos1;
    k_qscsel<<<dim3(24, 4, 2), 256, 0, stream>>>(PAIR, SCR, pin, pout, wlb, wlL, wlR,
                                                 xdst, Gbig, SCT, GI, b_ih, GHCP, b_hh,
                                                 15 - t, 0);
    k_sm<<<B, 256, 0, stream>>>(SCT, PAIR, xdst, v12, bw, c0s, out, A2, gb, t, 0);
    k_giup<<<dim3(24, 4, 4), 256, 0, stream>>>(A2, Wbig, GI, xdst);
    k_h1c<<<B, 256, 0, stream>>>(xdst, GI, b_hh, H1P);
    k_ghcs<<<dim3(24, 4, 2), 256, 0, stream>>>(xdst, H1P, W_hh, GHCP);
    k_pairc<<<NWS, 256, 0, stream>>>(wlb, wlL, wlR, GI, GHCP, H1P, w_fc, b_fc, PAIR, SCR);
  }

  // ---- final: h2 = PAIR[b][pos0[b*16]]; attention, scores+loss straight to out ----
  k_qscsel<<<dim3(24, 4, 2), 256, 0, stream>>>(PAIR, SCR, pos0, pos1, wlb, wlL, wlR,
                                               xdst, Gbig, SCT, GI, b_ih, GHCP, b_hh,
                                               1, 1);
  k_sm<<<B, 256, 0, stream>>>(SCT, PAIR, xdst, v12, bw, c0s, out, A2, gb, 15, 1);
}